// Round 14
// baseline (677.953 us; speedup 1.0000x reference)
//
#include <hip/hip_runtime.h>
#include <math.h>

// ---------------- problem constants ----------------
#define TT_   1000
#define TTOT_ 1100
#define NPAD_ 100
#define DD_   256
#define NN_   256

// workspace layout (float units)
#define X_OFF    0u
#define XB_OFF   4096000u
#define O_OFF    6144000u
#define BIG_OFF  12288000u
#define WT_OFF   20480000u
#define PE_OFF   22085632u
#define PP_OFF   22341632u
#define PL_OFF   (PP_OFF + 32768u)
#define CF_OFF   (PL_OFF + 4096u)
#define CB_OFF   (CF_OFF + 1920u)
#define BQ_OFF   (CF_OFF + 1920u + 5120u)
#define STL_OFF  (BQ_OFF + 3072u)

#define SC2_ 0.25503902254649546f   // (1/sqrt(32)) * log2(e)

typedef __attribute__((ext_vector_type(8))) short s16x8;
typedef __attribute__((ext_vector_type(4))) float f32x4;
typedef __attribute__((ext_vector_type(16))) float f32x16;
typedef __attribute__((ext_vector_type(4))) unsigned u32x4;

__device__ inline short f2bf(float f) {
    unsigned u = __float_as_uint(f);
    u += 0x7fffu + ((u >> 16) & 1u);
    return (short)(u >> 16);
}
__device__ inline float exp2i(float x) {
    float r; asm("v_exp_f32 %0, %1" : "=v"(r) : "v"(x)); return r;
}
// tanh-based GELU: max abs err ~3e-4; 1 transcendental.
__device__ inline float gelu_f(float v) {
    const float t = v * (0.7978845608f + 0.0356774081f * v * v);
    const float e = exp2i(t * 2.885390082f);          // e^{2t}
    const float th = 1.f - 2.f / (e + 1.f);
    return 0.5f * v * (1.f + th);
}

__device__ inline void gl_lds16(const short* g, short* l) {
    __builtin_amdgcn_global_load_lds(
        (const __attribute__((address_space(1))) void*)g,
        (__attribute__((address_space(3))) void*)l, 16, 0, 0);
}

// ---------------- weight transpose-convert ----------------
__global__ __launch_bounds__(256) void wtr_k(const float* __restrict__ in,
                                             short* __restrict__ out, int K, int N,
                                             int qrows, float qs)
{
    __shared__ float t[32][33];
    const int n0 = blockIdx.x * 32, k0 = blockIdx.y * 32;
    in  += (size_t)blockIdx.z * K * N;
    out += (size_t)blockIdx.z * K * N;
    const int tx = threadIdx.x & 31, ty = threadIdx.x >> 5;
    #pragma unroll
    for (int i = 0; i < 4; ++i)
        t[ty + 8 * i][tx] = in[(size_t)(k0 + ty + 8 * i) * N + n0 + tx];
    __syncthreads();
    #pragma unroll
    for (int i = 0; i < 4; ++i) {
        const int row = n0 + ty + 8 * i;
        float f = t[tx][ty + 8 * i];
        if (row < qrows) f *= qs;
        out[(size_t)row * K + k0 + tx] = f2bf(f);
    }
}

// ---------------- Y transpose-convert ----------------
__global__ __launch_bounds__(256) void ytr_k(const float* __restrict__ Y,
                                             short* __restrict__ out)
{
    __shared__ float t[32][33];
    const int b = blockIdx.z;
    const int t0 = blockIdx.x * 32, n0 = blockIdx.y * 32;
    const int tx = threadIdx.x & 31, ty = threadIdx.x >> 5;
    #pragma unroll
    for (int i = 0; i < 4; ++i) {
        const int tt = t0 + tx;
        t[ty + 8 * i][tx] = (tt < TT_)
            ? Y[((size_t)(b * NN_ + n0 + ty + 8 * i)) * TTOT_ + NPAD_ + tt] : 0.f;
    }
    __syncthreads();
    #pragma unroll
    for (int i = 0; i < 4; ++i) {
        const int tt = t0 + ty + 8 * i;
        if (tt < TT_)
            out[((size_t)(b * TT_ + tt)) * NN_ + n0 + tx] = f2bf(t[tx][ty + 8 * i]);
    }
}

// ---------------- positional-encoding table ----------------
__global__ void pe_k(float* __restrict__ PE)
{
    const int t = blockIdx.x, d = threadIdx.x;
    const float div = __expf(-(float)(d & ~1) * 0.0269834190585241f);
    const float ang = (float)t * div;
    PE[t * 256 + d] = (d & 1) ? cosf(ang) : sinf(ang);
}

// ---------------- scaled bias copy ----------------
__global__ void bscale_k(const float* __restrict__ in, float* __restrict__ out)
{
    const int i = blockIdx.x * 256 + threadIdx.x;
    if (i < 3072) {
        const int col = i % 768;
        out[i] = in[i] * ((col < 256) ? SC2_ : 1.f);
    }
}

// ---------------- bf16 MFMA GEMM (64x128, single-buffer) — embed only ----------------
template<int OUTBF, int ACT, int RES, int DUAL>
__global__ __launch_bounds__(256) void bgemm_k(const short* __restrict__ A,
                                               const short* __restrict__ Bt,
                                               const float* __restrict__ bias,
                                               const float* __restrict__ resid,
                                               void* __restrict__ Cout,
                                               short* __restrict__ Cb,
                                               int M, int N, int K, int nby)
{
    __shared__ short As[64 * 64];
    __shared__ short Bs[128 * 64];
    const int tid = threadIdx.x;

    const int nwg = gridDim.x;
    int gid = blockIdx.x;
    {
        const int q = nwg >> 3, r = nwg & 7;
        const int x = gid & 7, idx = gid >> 3;
        gid = (x < r ? x * (q + 1) : r * (q + 1) + (x - r) * q) + idx;
    }
    const int bx = gid / nby, by = gid - bx * nby;
    const int m0 = bx * 64, n0 = by * 128;

    const int wv = tid >> 6, lane = tid & 63;
    const int wr = wv >> 1, wc = wv & 1;
    const int l15 = lane & 15, lg = lane >> 4;

    f32x4 acc[2][4];
    #pragma unroll
    for (int i = 0; i < 2; ++i)
        #pragma unroll
        for (int j = 0; j < 4; ++j) acc[i][j] = (f32x4){0.f, 0.f, 0.f, 0.f};

    const int nt = K >> 6;
    for (int t = 0; t < nt; ++t) {
        __syncthreads();
        const int k0 = t << 6;
        #pragma unroll
        for (int i = 0; i < 2; ++i) {
            const int cid = i * 256 + tid;
            const int r = cid >> 3, c = cid & 7;
            gl_lds16(A + (size_t)(m0 + r) * K + k0 + ((c ^ (r & 7)) * 8), As + cid * 8);
        }
        #pragma unroll
        for (int i = 0; i < 4; ++i) {
            const int cid = i * 256 + tid;
            const int r = cid >> 3, c = cid & 7;
            gl_lds16(Bt + (size_t)(n0 + r) * K + k0 + ((c ^ (r & 7)) * 8), Bs + cid * 8);
        }
        __syncthreads();

        #pragma unroll
        for (int ks = 0; ks < 2; ++ks) {
            s16x8 af[2], bf[4];
            #pragma unroll
            for (int mi = 0; mi < 2; ++mi) {
                const int row = wr * 32 + mi * 16 + l15;
                const int ch = ks * 4 + lg;
                af[mi] = *(const s16x8*)(As + row * 64 + ((ch ^ (row & 7)) * 8));
            }
            #pragma unroll
            for (int ni = 0; ni < 4; ++ni) {
                const int col = wc * 64 + ni * 16 + l15;
                const int ch = ks * 4 + lg;
                bf[ni] = *(const s16x8*)(Bs + col * 64 + ((ch ^ (col & 7)) * 8));
            }
            #pragma unroll
            for (int mi = 0; mi < 2; ++mi)
                #pragma unroll
                for (int ni = 0; ni < 4; ++ni)
                    acc[mi][ni] = __builtin_amdgcn_mfma_f32_16x16x32_bf16(
                        af[mi], bf[ni], acc[mi][ni], 0, 0, 0);
        }
    }

    #pragma unroll
    for (int mi = 0; mi < 2; ++mi) {
        #pragma unroll
        for (int ni = 0; ni < 4; ++ni) {
            const int col = n0 + wc * 64 + ni * 16 + l15;
            const float bv = bias[col];
            #pragma unroll
            for (int r = 0; r < 4; ++r) {
                const int row = m0 + wr * 32 + mi * 16 + lg * 4 + r;
                float v = acc[mi][ni][r] + bv;
                if (RES == 1) v += resid[(size_t)row * N + col];
                if (RES == 2) v += resid[(size_t)(row % 1000) * N + col];
                if (ACT) v = 0.5f * v * (1.0f + erff(v * 0.70710678118654752f));
                if (OUTBF) ((short*)Cout)[(size_t)row * N + col] = f2bf(v);
                else       ((float*)Cout)[(size_t)row * N + col] = v;
                if (DUAL)  Cb[(size_t)row * N + col] = f2bf(v);
            }
        }
    }
}

// ---------------- L2-direct bf16 GEMM (64x128, no LDS staging, no K-loop barriers) ----------------
// All operands L2-resident; fragments loaded straight from global. KC compile-time.
template<int ACT, int KC>
__global__ __launch_bounds__(256) void bgemm_l2_k(const short* __restrict__ A,
                                                  const short* __restrict__ Bt,
                                                  const float* __restrict__ bias,
                                                  short* __restrict__ Cout,
                                                  int M, int N, int nby)
{
    __shared__ short Cs[64 * 132];
    const int tid = threadIdx.x;

    const int nwg = gridDim.x;
    int gid = blockIdx.x;
    {
        const int q = nwg >> 3, r = nwg & 7;
        const int x = gid & 7, idx = gid >> 3;
        gid = (x < r ? x * (q + 1) : r * (q + 1) + (x - r) * q) + idx;
    }
    const int bx = gid / nby, by = gid - bx * nby;
    const int m0 = bx * 64, n0 = by * 128;

    const int wv = tid >> 6, lane = tid & 63;
    const int wr = wv >> 1, wc = wv & 1;
    const int l15 = lane & 15, lg = lane >> 4;

    const short* Ap = A + (size_t)(m0 + wr * 32 + l15) * KC + lg * 8;
    const short* Bp = Bt + (size_t)(n0 + wc * 64 + l15) * KC + lg * 8;

    f32x4 acc[2][4];
    #pragma unroll
    for (int i = 0; i < 2; ++i)
        #pragma unroll
        for (int j = 0; j < 4; ++j) acc[i][j] = (f32x4){0.f, 0.f, 0.f, 0.f};

    #pragma unroll
    for (int k0 = 0; k0 < KC; k0 += 32) {
        s16x8 af[2], bf[4];
        #pragma unroll
        for (int mi = 0; mi < 2; ++mi)
            af[mi] = *(const s16x8*)(Ap + (size_t)mi * 16 * KC + k0);
        #pragma unroll
        for (int ni = 0; ni < 4; ++ni)
            bf[ni] = *(const s16x8*)(Bp + (size_t)ni * 16 * KC + k0);
        #pragma unroll
        for (int mi = 0; mi < 2; ++mi)
            #pragma unroll
            for (int ni = 0; ni < 4; ++ni)
                acc[mi][ni] = __builtin_amdgcn_mfma_f32_16x16x32_bf16(
                    af[mi], bf[ni], acc[mi][ni], 0, 0, 0);
    }

    // epilogue: bias(+gelu) -> LDS [64][132] -> coalesced dwordx4 stores
    #pragma unroll
    for (int mi = 0; mi < 2; ++mi)
        #pragma unroll
        for (int ni = 0; ni < 4; ++ni) {
            const int cl = wc * 64 + ni * 16 + l15;
            const float bv = bias[n0 + cl];
            #pragma unroll
            for (int r = 0; r < 4; ++r) {
                const int rl = wr * 32 + mi * 16 + lg * 4 + r;
                float v = acc[mi][ni][r] + bv;
                if (ACT) v = gelu_f(v);
                Cs[rl * 132 + cl] = f2bf(v);
            }
        }
    __syncthreads();
    #pragma unroll
    for (int i = 0; i < 4; ++i) {
        const int cid = i * 256 + tid;
        const int rl = cid >> 4, cc = (cid & 15) * 8;
        s16x8 vv = *(const s16x8*)(Cs + rl * 132 + cc);
        *(s16x8*)(Cout + (size_t)(m0 + rl) * N + n0 + cc) = vv;
    }
}

// ---------------- fused GEMM(32x256 full-row) + resid + LayerNorm ----------------
__global__ __launch_bounds__(512) void bgemmln_k(const short* __restrict__ A,
                                                 const short* __restrict__ Bt,
                                                 const float* __restrict__ bias,
                                                 const float* __restrict__ lng,
                                                 const float* __restrict__ lnb,
                                                 float* __restrict__ X,
                                                 short* __restrict__ Xb,
                                                 int K)
{
    __shared__ short As[32 * 64];
    __shared__ short Bs[256 * 64];
    __shared__ float red[32][4][2];
    __shared__ float mrs[32][2];
    const int tid = threadIdx.x;

    const int nwg = gridDim.x;
    int gid = blockIdx.x;
    {
        const int q = nwg >> 3, r = nwg & 7;
        const int x = gid & 7, idx = gid >> 3;
        gid = (x < r ? x * (q + 1) : r * (q + 1) + (x - r) * q) + idx;
    }
    const int m0 = gid * 32;

    const int wv = tid >> 6, lane = tid & 63;
    const int wr = wv >> 2, wcx = wv & 3;
    const int l15 = lane & 15, lg = lane >> 4;

    f32x4 acc[4];
    #pragma unroll
    for (int j = 0; j < 4; ++j) acc[j] = (f32x4){0.f, 0.f, 0.f, 0.f};

    const int nt = K >> 6;
    for (int t = 0; t < nt; ++t) {
        __syncthreads();
        const int k0 = t << 6;
        if (tid < 256) {
            const int r = tid >> 3, c = tid & 7;
            gl_lds16(A + (size_t)(m0 + r) * K + k0 + ((c ^ (r & 7)) * 8), As + tid * 8);
        }
        #pragma unroll
        for (int i = 0; i < 4; ++i) {
            const int cid = i * 512 + tid;
            const int r = cid >> 3, c = cid & 7;
            gl_lds16(Bt + (size_t)r * K + k0 + ((c ^ (r & 7)) * 8), Bs + cid * 8);
        }
        __syncthreads();

        #pragma unroll
        for (int ks = 0; ks < 2; ++ks) {
            s16x8 af, bf[4];
            {
                const int row = wr * 16 + l15;
                const int ch = ks * 4 + lg;
                af = *(const s16x8*)(As + row * 64 + ((ch ^ (row & 7)) * 8));
            }
            #pragma unroll
            for (int ni = 0; ni < 4; ++ni) {
                const int col = wcx * 64 + ni * 16 + l15;
                const int ch = ks * 4 + lg;
                bf[ni] = *(const s16x8*)(Bs + col * 64 + ((ch ^ (col & 7)) * 8));
            }
            #pragma unroll
            for (int ni = 0; ni < 4; ++ni)
                acc[ni] = __builtin_amdgcn_mfma_f32_16x16x32_bf16(af, bf[ni], acc[ni], 0, 0, 0);
        }
    }

    float v[4][4];
    #pragma unroll
    for (int ni = 0; ni < 4; ++ni) {
        const int col = wcx * 64 + ni * 16 + l15;
        const float bv = bias[col];
        #pragma unroll
        for (int r = 0; r < 4; ++r) {
            const int row = m0 + wr * 16 + lg * 4 + r;
            v[ni][r] = acc[ni][r] + bv + X[(size_t)row * 256 + col];
        }
    }

    #pragma unroll
    for (int r = 0; r < 4; ++r) {
        float ss = v[0][r] + v[1][r] + v[2][r] + v[3][r];
        float qq = v[0][r] * v[0][r] + v[1][r] * v[1][r]
                 + v[2][r] * v[2][r] + v[3][r] * v[3][r];
        #pragma unroll
        for (int msk = 1; msk < 16; msk <<= 1) {
            ss += __shfl_xor(ss, msk);
            qq += __shfl_xor(qq, msk);
        }
        if (l15 == 0) {
            const int rloc = wr * 16 + lg * 4 + r;
            red[rloc][wcx][0] = ss;
            red[rloc][wcx][1] = qq;
        }
    }
    __syncthreads();
    if (tid < 32) {
        const float s = red[tid][0][0] + red[tid][1][0] + red[tid][2][0] + red[tid][3][0];
        const float q = red[tid][0][1] + red[tid][1][1] + red[tid][2][1] + red[tid][3][1];
        const float mean = s * (1.f / 256.f);
        const float var = q * (1.f / 256.f) - mean * mean;
        mrs[tid][0] = mean;
        mrs[tid][1] = rsqrtf(var + 1e-5f);
    }
    __syncthreads();

    #pragma unroll
    for (int ni = 0; ni < 4; ++ni) {
        const int col = wcx * 64 + ni * 16 + l15;
        const float gg = lng[col], bb = lnb[col];
        #pragma unroll
        for (int r = 0; r < 4; ++r) {
            const int rloc = wr * 16 + lg * 4 + r;
            const int row = m0 + rloc;
            const float o = (v[ni][r] - mrs[rloc][0]) * mrs[rloc][1] * gg + bb;
            X[(size_t)row * 256 + col] = o;
            Xb[(size_t)row * 256 + col] = f2bf(o);
        }
    }
}

// ---------------- MFMA flash attention ----------------
__global__ __launch_bounds__(512) void mattn_k(const short* __restrict__ qkv,
                                               short* __restrict__ o)
{
    int wg = blockIdx.x;
    wg = (wg & 7) * 64 + (wg >> 3);
    const int qt = wg & 3, h = (wg >> 2) & 7, b = wg >> 5;

    const int tid = threadIdx.x, wv = tid >> 6, lane = tid & 63;
    const int q31 = lane & 31, hi = lane >> 5;
    __shared__ short Ks[2][64 * 40];
    __shared__ short VT[2][32 * 72];

    const int q0w = qt * 256 + wv * 32;
    int qrow = q0w + q31; if (qrow > 999) qrow = 999;
    s16x8 bq[2];
    #pragma unroll
    for (int dh = 0; dh < 2; ++dh)
        bq[dh] = *(const s16x8*)(qkv + ((size_t)(b * TT_ + qrow)) * 768 + h * 32 + dh * 16 + hi * 8);

    f32x16 oacc;
    #pragma unroll
    for (int i = 0; i < 16; ++i) oacc[i] = 0.f;
    float lrun = 0.f;

    const int sr = tid >> 2, sc = tid & 3;
    const int u = tid & 255;
    const int kp = u >> 3, dq = (u & 7) * 4;
    s16x8 kreg;
    short4 va, vb;
    auto LOADT = [&](int kt) {
        if (tid < 256) {
            int t = kt * 64 + sr; if (t > 999) t = 999;
            kreg = *(const s16x8*)(qkv + ((size_t)(b * TT_ + t)) * 768 + 256 + h * 32 + sc * 8);
        } else {
            int t0 = kt * 64 + 2 * kp, t1 = t0 + 1;
            if (t0 > 999) t0 = 999;
            if (t1 > 999) t1 = 999;
            va = *(const short4*)(qkv + ((size_t)(b * TT_ + t0)) * 768 + 512 + h * 32 + dq);
            vb = *(const short4*)(qkv + ((size_t)(b * TT_ + t1)) * 768 + 512 + h * 32 + dq);
        }
    };
    auto WRITET = [&](int buf) {
        if (tid < 256) {
            *(s16x8*)(&Ks[buf][sr * 40 + sc * 8]) = kreg;
        } else {
            const int c = kp >> 2;
            const int ko = (2 * kp) & 7;
            const uint2 vaw = *(const uint2*)&va;
            const uint2 vbw = *(const uint2*)&vb;
            unsigned pk[4];
            pk[0] = __builtin_amdgcn_perm(vbw.x, vaw.x, 0x05040100u);
            pk[1] = __builtin_amdgcn_perm(vbw.x, vaw.x, 0x07060302u);
            pk[2] = __builtin_amdgcn_perm(vbw.y, vaw.y, 0x05040100u);
            pk[3] = __builtin_amdgcn_perm(vbw.y, vaw.y, 0x07060302u);
            #pragma unroll
            for (int j = 0; j < 4; ++j) {
                const int d = dq + j;
                *(unsigned*)(&VT[buf][d * 72 + ((c ^ (d >> 3)) * 8) + ko]) = pk[j];
            }
        }
    };

    LOADT(0); WRITET(0);
    __syncthreads();
    int cur = 0;

    for (int kt = 0; kt < 16; ++kt) {
        if (kt < 15) LOADT(kt + 1);

        f32x16 st[2];
        __builtin_amdgcn_s_setprio(1);
        #pragma unroll
        for (int kb = 0; kb < 2; ++kb) {
            s16x8 kf0 = *(const s16x8*)(&Ks[cur][(kb * 32 + q31) * 40 + hi * 8]);
            s16x8 kf1 = *(const s16x8*)(&Ks[cur][(kb * 32 + q31) * 40 + 16 + hi * 8]);
            f32x16 z;
            #pragma unroll
            for (int i = 0; i < 16; ++i) z[i] = 0.f;
            z = __builtin_amdgcn_mfma_f32_32x32x16_bf16(kf0, bq[0], z, 0, 0, 0);
            z = __builtin_amdgcn_mfma_f32_32x32x16_bf16(kf1, bq[1], z, 0, 0, 0);
            st[kb] = z;
        }
        __builtin_amdgcn_s_setprio(0);

        if (kt == 15) {
            #pragma unroll
            for (int kb = 0; kb < 2; ++kb)
                #pragma unroll
                for (int r = 0; r < 16; ++r) {
                    const int kloc = kb * 32 + (r & 3) + 8 * (r >> 2) + 4 * hi;
                    if (960 + kloc >= TT_) st[kb][r] = -1e30f;
                }
        }

        float sloc = 0.f;
        #pragma unroll
        for (int kb = 0; kb < 2; ++kb)
            #pragma unroll
            for (int r = 0; r < 16; ++r) {
                const float p = exp2i(st[kb][r]);
                st[kb][r] = p; sloc += p;
            }
        lrun += sloc;

        unsigned wk[2][4][2];
        #pragma unroll
        for (int kb = 0; kb < 2; ++kb)
            #pragma unroll
            for (int a = 0; a < 4; ++a)
                #pragma unroll
                for (int h2 = 0; h2 < 2; ++h2) {
                    unsigned rr;
                    asm("v_cvt_pk_bf16_f32 %0, %1, %2"
                        : "=v"(rr)
                        : "v"(st[kb][4 * a + 2 * h2]), "v"(st[kb][4 * a + 2 * h2 + 1]));
                    wk[kb][a][h2] = rr;
                }

        #pragma unroll
        for (int ks = 0; ks < 4; ++ks) {
            const int kb = ks >> 1, qq = ks & 1;
            unsigned X0 = wk[kb][2 * qq + 1][0], Y0 = wk[kb][2 * qq][0];
            unsigned X1 = wk[kb][2 * qq + 1][1], Y1 = wk[kb][2 * qq][1];
            asm("v_permlane32_swap_b32 %0, %1" : "+v"(X0), "+v"(Y0));
            asm("v_permlane32_swap_b32 %0, %1" : "+v"(X1), "+v"(Y1));
            u32x4 w4 = (u32x4){Y0, Y1, X0, X1};
            s16x8 pb = __builtin_bit_cast(s16x8, w4);
            s16x8 vf = *(const s16x8*)(&VT[cur][q31 * 72 + (((2 * ks + hi) ^ (q31 >> 3)) * 8)]);
            __builtin_amdgcn_s_setprio(1);
            oacc = __builtin_amdgcn_mfma_f32_32x32x16_bf16(vf, pb, oacc, 0, 0, 0);
            __builtin_amdgcn_s_setprio(0);
        }

        if (kt < 15) WRITET(cur ^ 1);
        __syncthreads();
        cur ^= 1;
    }

    lrun += __shfl_xor(lrun, 32);

    const int t = q0w + q31;
    if (t < TT_) {
        const float inv = 1.f / lrun;
        short* ob = o + ((size_t)(b * TT_ + t)) * 256 + h * 32;
        #pragma unroll
        for (int a = 0; a < 4; ++a) {
            unsigned w0, w1;
            asm("v_cvt_pk_bf16_f32 %0, %1, %2"
                : "=v"(w0) : "v"(oacc[4 * a + 0] * inv), "v"(oacc[4 * a + 1] * inv));
            asm("v_cvt_pk_bf16_f32 %0, %1, %2"
                : "=v"(w1) : "v"(oacc[4 * a + 2] * inv), "v"(oacc[4 * a + 3] * inv));
            const int d0 = 8 * a + 4 * hi;
            *(unsigned*)(ob + d0) = w0;
            *(unsigned*)(ob + d0 + 2) = w1;
        }
    }
}

// ---------------- mean pool ----------------
__global__ __launch_bounds__(256) void pool_part_k(const float* __restrict__ X,
                                                   float* __restrict__ partial)
{
    const int b = blockIdx.x, seg = blockIdx.y, d = threadIdx.x;
    float s = 0.f;
    const int t0 = seg * 125;
    for (int t = t0; t < t0 + 125; ++t) s += X[((size_t)b * TT_ + t) * 256 + d];
    partial[(b * 8 + seg) * 256 + d] = s;
}
__global__ __launch_bounds__(256) void pool_red_k(const float* __restrict__ partial,
                                                  float* __restrict__ pooled)
{
    const int b = blockIdx.x, d = threadIdx.x;
    float s = 0.f;
    for (int k = 0; k < 8; ++k) s += partial[(b * 8 + k) * 256 + d];
    pooled[b * 256 + d] = s * (1.f / (float)TT_);
}

// ---------------- decode head ----------------
__global__ __launch_bounds__(128) void head_k(const float* __restrict__ pooled,
                                              const float* __restrict__ toLW,
                                              const float* __restrict__ toLb,
                                              const float* __restrict__ dW1,
                                              const float* __restrict__ db1,
                                              const float* __restrict__ dW2,
                                              const float* __restrict__ db2,
                                              float* __restrict__ coeffs)
{
    const int b = blockIdx.x, j = threadIdx.x;
    __shared__ float hs[64];
    __shared__ float hid[128];
    float a = toLb[j];
    for (int d = 0; d < 256; ++d) a += pooled[b * 256 + d] * toLW[d * 128 + j];
    if (j < 64) hs[j] = a;
    __syncthreads();
    float a2 = db1[j];
    for (int z = 0; z < 64; ++z) a2 += hs[z] * dW1[z * 128 + j];
    hid[j] = fmaxf(a2, 0.f);
    __syncthreads();
    if (j < 120) {
        float a3 = db2[j];
        for (int k = 0; k < 128; ++k) a3 += hid[k] * dW2[k * 120 + j];
        coeffs[b * 120 + j] = a3;
    }
}

// ---------------- combined conv kernel ----------------
__global__ void comb_k(const float* __restrict__ selfK,
                       const float* __restrict__ cplW,
                       const float* __restrict__ cplB,
                       float* __restrict__ comb)
{
    const int n = threadIdx.x;
    for (int ti = 0; ti < 20; ++ti) {
        float s = selfK[ti * 256 + n];
        #pragma unroll
        for (int si = 0; si < 4; ++si) s += cplW[n * 4 + si] * cplB[ti * 4 + si];
        comb[n * 20 + ti] = s;
    }
}

// ---------------- sti_lat ----------------
__global__ __launch_bounds__(256) void stilat_k(const float* __restrict__ SB,
                                                const float* __restrict__ coeffs,
                                                float* __restrict__ STL)
{
    const int bf = blockIdx.x;
    __shared__ float c[30];
    if (threadIdx.x < 30) c[threadIdx.x] = coeffs[(bf >> 2) * 120 + (bf & 3) * 30 + threadIdx.x];
    __syncthreads();
    for (int t = threadIdx.x; t < TT_; t += 256) {
        float acc = 0.f;
        const float* sp = SB + (size_t)t * 30;
        #pragma unroll
        for (int k = 0; k < 30; ++k) acc += c[k] * sp[k];
        STL[bf * TT_ + t] = acc;
    }
}

// ---------------- final ----------------
__global__ __launch_bounds__(256) void final_k(const float* __restrict__ Y,
                                               const float* __restrict__ STL,
                                               const float* __restrict__ roW,
                                               const float* __restrict__ comb,
                                               float* __restrict__ out)
{
    const int bx = blockIdx.x;
    const int ts = bx & 3, nc = (bx >> 2) & 31, b = bx >> 7;
    const int n0 = nc * 8, t0 = ts * 250;
    const int tid = threadIdx.x;
    __shared__ float rw[8][4], ck[8][20], yl[8][272];

    if (tid < 32) rw[tid >> 2][tid & 3] = roW[(n0 + (tid >> 2)) * 4 + (tid & 3)];
    if (tid >= 64 && tid < 224) {
        const int j = tid - 64;
        ck[j / 20][j % 20] = comb[(n0 + j / 20) * 20 + (j % 20)];
    }
    for (int j = tid; j < 2160; j += 256) {
        const int n = j / 270, jj = j - n * 270;
        yl[n][jj] = Y[((size_t)(b * 256 + n0 + n)) * TTOT_ + t0 + 80 + jj];
    }
    __syncthreads();

    if (tid < 250) {
        const int t = t0 + tid;
        float s4[4];
        #pragma unroll
        for (int f = 0; f < 4; ++f) s4[f] = STL[((size_t)b * 4 + f) * TT_ + t];
        #pragma unroll
        for (int n = 0; n < 8; ++n) {
            float acc = rw[n][0] * s4[0] + rw[n][1] * s4[1]
                      + rw[n][2] * s4[2] + rw[n][3] * s4[3];
            #pragma unroll
            for (int tau = 1; tau <= 20; ++tau)
                acc += ck[n][tau - 1] * yl[n][tid + 20 - tau];
            out[((size_t)(b * 256 + n0 + n)) * TT_ + t] = acc;
        }
    }
}

// ---------------- launch ----------------
extern "C" void kernel_launch(void* const* d_in, const int* in_sizes, int n_in,
                              void* d_out, int out_size, void* d_ws, size_t ws_size,
                              hipStream_t stream)
{
    const float* Y      = (const float*)d_in[0];
    const float* tokW   = (const float*)d_in[1];
    const float* tokb   = (const float*)d_in[2];
    const float* Wqkv   = (const float*)d_in[3];
    const float* bqkv   = (const float*)d_in[4];
    const float* Wo     = (const float*)d_in[5];
    const float* bo     = (const float*)d_in[6];
    const float* ln1g   = (const float*)d_in[7];
    const float* ln1b   = (const float*)d_in[8];
    const float* W1     = (const float*)d_in[9];
    const float* b1     = (const float*)d_in[10];
    const float* W2     = (const float*)d_in[11];
    const float* b2     = (const float*)d_in[12];
    const float* ln2g   = (const float*)d_in[13];
    const float* ln2b   = (const float*)d_in[14];
    const float* toLW   = (const float*)d_in[15];
    const float* toLb   = (const float*)d_in[16];
    const float* dW1    = (const float*)d_in[17];
    const float* db1    = (const float*)d_in[18];
    const float* dW2    = (const float*)d_in[19];
    const float* db2    = (const float*)d_in[20];
    const float* SB     = (const float*)d_in[21];
    const float* roW    = (const float*)d_in[22];
    const float* cplW   = (const float*)d_in[23];
    const float* cplB   = (const float*)d_in[24];
    const float* selfK  = (const float*)d_in[25];

    float* ws  = (float*)d_ws;
    float* X   = ws + X_OFF;
    short* Xb  = (short*)(ws + XB_OFF);
    short* O   = (short*)(ws + O_OFF);
    short* BIG = (short*)(ws + BIG_OFF);
    short* WT  = (short*)(ws + WT_OFF);
    float* PE  = ws + PE_OFF;
    float* PP  = ws + PP_OFF;
    float* PL  = ws + PL_OFF;
    float* CF  = ws + CF_OFF;
    float* CB  = ws + CB_OFF;
    float* BQ  = ws + BQ_OFF;
    float* STL = ws + STL_OFF;

    short* WTqkv = WT;
    short* WTo   = WT + 786432;
    short* WTw1  = WT + 1048576;
    short* WTw2  = WT + 2097152;
    short* WTtok = WT + 3145728;
    short* Ybt   = BIG;

    wtr_k<<<dim3(24, 8, 4), 256, 0, stream>>>(Wqkv, WTqkv, 256, 768, 256, SC2_);
    wtr_k<<<dim3(8, 8, 4),  256, 0, stream>>>(Wo,   WTo,   256, 256, 0, 1.f);
    wtr_k<<<dim3(32, 8, 4), 256, 0, stream>>>(W1,   WTw1,  256, 1024, 0, 1.f);
    wtr_k<<<dim3(8, 32, 4), 256, 0, stream>>>(W2,   WTw2,  1024, 256, 0, 1.f);
    wtr_k<<<dim3(8, 8, 1),  256, 0, stream>>>(tokW, WTtok, 256, 256, 0, 1.f);
    bscale_k<<<12, 256, 0, stream>>>(bqkv, BQ);
    pe_k<<<1000, 256, 0, stream>>>(PE);
    ytr_k<<<dim3(32, 8, 16), 256, 0, stream>>>(Y, Ybt);

    bgemm_k<0, 0, 2, 1><<<500, 256, 0, stream>>>(
        Ybt, WTtok, tokb, PE, X, Xb, 16000, 256, 256, 2);

    for (int l = 0; l < 4; ++l) {
        bgemm_l2_k<0, 256><<<1500, 256, 0, stream>>>(
            Xb, WTqkv + (size_t)l * 196608, BQ + l * 768, BIG,
            16000, 768, 6);
        mattn_k<<<512, 512, 0, stream>>>(BIG, O);
        bgemmln_k<<<500, 512, 0, stream>>>(
            O, WTo + (size_t)l * 65536, bo + l * 256,
            ln1g + l * 256, ln1b + l * 256, X, Xb, 256);
        bgemm_l2_k<1, 256><<<2000, 256, 0, stream>>>(
            Xb, WTw1 + (size_t)l * 262144, b1 + l * 1024, BIG,
            16000, 1024, 8);
        bgemmln_k<<<500, 512, 0, stream>>>(
            BIG, WTw2 + (size_t)l * 262144, b2 + l * 256,
            ln2g + l * 256, ln2b + l * 256, X, Xb, 1024);
    }

    pool_part_k<<<dim3(16, 8), 256, 0, stream>>>(X, PP);
    pool_red_k<<<16, 256, 0, stream>>>(PP, PL);
    head_k<<<16, 128, 0, stream>>>(PL, toLW, toLb, dW1, db1, dW2, db2, CF);
    comb_k<<<1, 256, 0, stream>>>(selfK, cplW, cplB, CB);
    stilat_k<<<64, 256, 0, stream>>>(SB, CF, STL);
    final_k<<<2048, 256, 0, stream>>>(Y, STL, roW, CB, (float*)d_out);
}

// Round 15
// 498.356 us; speedup vs baseline: 1.3604x; 1.3604x over previous
//
#include <hip/hip_runtime.h>
#include <math.h>

// ---------------- problem constants ----------------
#define TT_   1000
#define TTOT_ 1100
#define NPAD_ 100
#define DD_   256
#define NN_   256

// workspace layout (float units)
#define X_OFF    0u
#define XB_OFF   4096000u
#define O_OFF    6144000u
#define BIG_OFF  12288000u
#define WT_OFF   20480000u
#define PE_OFF   22085632u
#define PP_OFF   22341632u
#define PL_OFF   (PP_OFF + 32768u)
#define CF_OFF   (PL_OFF + 4096u)
#define CB_OFF   (CF_OFF + 1920u)
#define BQ_OFF   (CF_OFF + 1920u + 5120u)
#define STL_OFF  (BQ_OFF + 3072u)

#define SC2_ 0.25503902254649546f   // (1/sqrt(32)) * log2(e)

typedef __attribute__((ext_vector_type(8))) short s16x8;
typedef __attribute__((ext_vector_type(4))) float f32x4;
typedef __attribute__((ext_vector_type(16))) float f32x16;
typedef __attribute__((ext_vector_type(4))) unsigned u32x4;

__device__ inline short f2bf(float f) {
    unsigned u = __float_as_uint(f);
    u += 0x7fffu + ((u >> 16) & 1u);
    return (short)(u >> 16);
}
__device__ inline float exp2i(float x) {
    float r; asm("v_exp_f32 %0, %1" : "=v"(r) : "v"(x)); return r;
}
// tanh-based GELU: max abs err ~3e-4; 1 transcendental.
__device__ inline float gelu_f(float v) {
    const float t = v * (0.7978845608f + 0.0356774081f * v * v);
    const float e = exp2i(t * 2.885390082f);          // e^{2t}
    const float th = 1.f - 2.f / (e + 1.f);
    return 0.5f * v * (1.f + th);
}

__device__ inline void gl_lds16(const short* g, short* l) {
    __builtin_amdgcn_global_load_lds(
        (const __attribute__((address_space(1))) void*)g,
        (__attribute__((address_space(3))) void*)l, 16, 0, 0);
}

// ---------------- weight transpose-convert ----------------
__global__ __launch_bounds__(256) void wtr_k(const float* __restrict__ in,
                                             short* __restrict__ out, int K, int N,
                                             int qrows, float qs)
{
    __shared__ float t[32][33];
    const int n0 = blockIdx.x * 32, k0 = blockIdx.y * 32;
    in  += (size_t)blockIdx.z * K * N;
    out += (size_t)blockIdx.z * K * N;
    const int tx = threadIdx.x & 31, ty = threadIdx.x >> 5;
    #pragma unroll
    for (int i = 0; i < 4; ++i)
        t[ty + 8 * i][tx] = in[(size_t)(k0 + ty + 8 * i) * N + n0 + tx];
    __syncthreads();
    #pragma unroll
    for (int i = 0; i < 4; ++i) {
        const int row = n0 + ty + 8 * i;
        float f = t[tx][ty + 8 * i];
        if (row < qrows) f *= qs;
        out[(size_t)row * K + k0 + tx] = f2bf(f);
    }
}

// ---------------- Y transpose-convert ----------------
__global__ __launch_bounds__(256) void ytr_k(const float* __restrict__ Y,
                                             short* __restrict__ out)
{
    __shared__ float t[32][33];
    const int b = blockIdx.z;
    const int t0 = blockIdx.x * 32, n0 = blockIdx.y * 32;
    const int tx = threadIdx.x & 31, ty = threadIdx.x >> 5;
    #pragma unroll
    for (int i = 0; i < 4; ++i) {
        const int tt = t0 + tx;
        t[ty + 8 * i][tx] = (tt < TT_)
            ? Y[((size_t)(b * NN_ + n0 + ty + 8 * i)) * TTOT_ + NPAD_ + tt] : 0.f;
    }
    __syncthreads();
    #pragma unroll
    for (int i = 0; i < 4; ++i) {
        const int tt = t0 + ty + 8 * i;
        if (tt < TT_)
            out[((size_t)(b * TT_ + tt)) * NN_ + n0 + tx] = f2bf(t[tx][ty + 8 * i]);
    }
}

// ---------------- positional-encoding table ----------------
__global__ void pe_k(float* __restrict__ PE)
{
    const int t = blockIdx.x, d = threadIdx.x;
    const float div = __expf(-(float)(d & ~1) * 0.0269834190585241f);
    const float ang = (float)t * div;
    PE[t * 256 + d] = (d & 1) ? cosf(ang) : sinf(ang);
}

// ---------------- scaled bias copy ----------------
__global__ void bscale_k(const float* __restrict__ in, float* __restrict__ out)
{
    const int i = blockIdx.x * 256 + threadIdx.x;
    if (i < 3072) {
        const int col = i % 768;
        out[i] = in[i] * ((col < 256) ? SC2_ : 1.f);
    }
}

// ---------------- bf16 MFMA GEMM (64x128, single-buffer) — embed only ----------------
template<int OUTBF, int ACT, int RES, int DUAL>
__global__ __launch_bounds__(256) void bgemm_k(const short* __restrict__ A,
                                               const short* __restrict__ Bt,
                                               const float* __restrict__ bias,
                                               const float* __restrict__ resid,
                                               void* __restrict__ Cout,
                                               short* __restrict__ Cb,
                                               int M, int N, int K, int nby)
{
    __shared__ short As[64 * 64];
    __shared__ short Bs[128 * 64];
    const int tid = threadIdx.x;

    const int nwg = gridDim.x;
    int gid = blockIdx.x;
    {
        const int q = nwg >> 3, r = nwg & 7;
        const int x = gid & 7, idx = gid >> 3;
        gid = (x < r ? x * (q + 1) : r * (q + 1) + (x - r) * q) + idx;
    }
    const int bx = gid / nby, by = gid - bx * nby;
    const int m0 = bx * 64, n0 = by * 128;

    const int wv = tid >> 6, lane = tid & 63;
    const int wr = wv >> 1, wc = wv & 1;
    const int l15 = lane & 15, lg = lane >> 4;

    f32x4 acc[2][4];
    #pragma unroll
    for (int i = 0; i < 2; ++i)
        #pragma unroll
        for (int j = 0; j < 4; ++j) acc[i][j] = (f32x4){0.f, 0.f, 0.f, 0.f};

    const int nt = K >> 6;
    for (int t = 0; t < nt; ++t) {
        __syncthreads();
        const int k0 = t << 6;
        #pragma unroll
        for (int i = 0; i < 2; ++i) {
            const int cid = i * 256 + tid;
            const int r = cid >> 3, c = cid & 7;
            gl_lds16(A + (size_t)(m0 + r) * K + k0 + ((c ^ (r & 7)) * 8), As + cid * 8);
        }
        #pragma unroll
        for (int i = 0; i < 4; ++i) {
            const int cid = i * 256 + tid;
            const int r = cid >> 3, c = cid & 7;
            gl_lds16(Bt + (size_t)(n0 + r) * K + k0 + ((c ^ (r & 7)) * 8), Bs + cid * 8);
        }
        __syncthreads();

        #pragma unroll
        for (int ks = 0; ks < 2; ++ks) {
            s16x8 af[2], bf[4];
            #pragma unroll
            for (int mi = 0; mi < 2; ++mi) {
                const int row = wr * 32 + mi * 16 + l15;
                const int ch = ks * 4 + lg;
                af[mi] = *(const s16x8*)(As + row * 64 + ((ch ^ (row & 7)) * 8));
            }
            #pragma unroll
            for (int ni = 0; ni < 4; ++ni) {
                const int col = wc * 64 + ni * 16 + l15;
                const int ch = ks * 4 + lg;
                bf[ni] = *(const s16x8*)(Bs + col * 64 + ((ch ^ (col & 7)) * 8));
            }
            #pragma unroll
            for (int mi = 0; mi < 2; ++mi)
                #pragma unroll
                for (int ni = 0; ni < 4; ++ni)
                    acc[mi][ni] = __builtin_amdgcn_mfma_f32_16x16x32_bf16(
                        af[mi], bf[ni], acc[mi][ni], 0, 0, 0);
        }
    }

    #pragma unroll
    for (int mi = 0; mi < 2; ++mi) {
        #pragma unroll
        for (int ni = 0; ni < 4; ++ni) {
            const int col = n0 + wc * 64 + ni * 16 + l15;
            const float bv = bias[col];
            #pragma unroll
            for (int r = 0; r < 4; ++r) {
                const int row = m0 + wr * 32 + mi * 16 + lg * 4 + r;
                float v = acc[mi][ni][r] + bv;
                if (RES == 1) v += resid[(size_t)row * N + col];
                if (RES == 2) v += resid[(size_t)(row % 1000) * N + col];
                if (ACT) v = 0.5f * v * (1.0f + erff(v * 0.70710678118654752f));
                if (OUTBF) ((short*)Cout)[(size_t)row * N + col] = f2bf(v);
                else       ((float*)Cout)[(size_t)row * N + col] = v;
                if (DUAL)  Cb[(size_t)row * N + col] = f2bf(v);
            }
        }
    }
}

// ---------------- bf16 MFMA GEMM (64x128, dbuf, counted vmcnt) — qkv ----------------
template<int ACT>
__global__ __launch_bounds__(256) void bgemm_db_k(const short* __restrict__ A,
                                                  const short* __restrict__ Bt,
                                                  const float* __restrict__ bias,
                                                  short* __restrict__ Cout,
                                                  int M, int N, int K, int nby)
{
    __shared__ short SH[2 * 12288];
    const int tid = threadIdx.x;

    const int nwg = gridDim.x;
    int gid = blockIdx.x;
    {
        const int q = nwg >> 3, r = nwg & 7;
        const int x = gid & 7, idx = gid >> 3;
        gid = (x < r ? x * (q + 1) : r * (q + 1) + (x - r) * q) + idx;
    }
    const int bx = gid / nby, by = gid - bx * nby;
    const int m0 = bx * 64, n0 = by * 128;

    const int wv = tid >> 6, lane = tid & 63;
    const int wr = wv >> 1, wc = wv & 1;
    const int l15 = lane & 15, lg = lane >> 4;

    f32x4 acc[2][4];
    #pragma unroll
    for (int i = 0; i < 2; ++i)
        #pragma unroll
        for (int j = 0; j < 4; ++j) acc[i][j] = (f32x4){0.f, 0.f, 0.f, 0.f};

    auto STAGE = [&](int p, int k0) {
        short* dA = SH + p * 12288;
        short* dB = dA + 4096;
        #pragma unroll
        for (int i = 0; i < 2; ++i) {
            const int cid = i * 256 + tid;
            const int r = cid >> 3, c = cid & 7;
            gl_lds16(A + (size_t)(m0 + r) * K + k0 + ((c ^ (r & 7)) * 8), dA + cid * 8);
        }
        #pragma unroll
        for (int i = 0; i < 4; ++i) {
            const int cid = i * 256 + tid;
            const int r = cid >> 3, c = cid & 7;
            gl_lds16(Bt + (size_t)(n0 + r) * K + k0 + ((c ^ (r & 7)) * 8), dB + cid * 8);
        }
    };

    const int nt = K >> 6;
    STAGE(0, 0);
    int cur = 0;
    for (int t = 0; t < nt; ++t) {
        if (t + 1 < nt) {
            STAGE(cur ^ 1, (t + 1) << 6);
            asm volatile("s_waitcnt vmcnt(6)" ::: "memory");
        } else {
            asm volatile("s_waitcnt vmcnt(0)" ::: "memory");
        }
        __builtin_amdgcn_s_barrier();

        const short* Asb = SH + cur * 12288;
        const short* Bsb = Asb + 4096;
        #pragma unroll
        for (int ks = 0; ks < 2; ++ks) {
            s16x8 af[2], bf[4];
            #pragma unroll
            for (int mi = 0; mi < 2; ++mi) {
                const int row = wr * 32 + mi * 16 + l15;
                const int ch = ks * 4 + lg;
                af[mi] = *(const s16x8*)(Asb + row * 64 + ((ch ^ (row & 7)) * 8));
            }
            #pragma unroll
            for (int ni = 0; ni < 4; ++ni) {
                const int col = wc * 64 + ni * 16 + l15;
                const int ch = ks * 4 + lg;
                bf[ni] = *(const s16x8*)(Bsb + col * 64 + ((ch ^ (col & 7)) * 8));
            }
            #pragma unroll
            for (int mi = 0; mi < 2; ++mi)
                #pragma unroll
                for (int ni = 0; ni < 4; ++ni)
                    acc[mi][ni] = __builtin_amdgcn_mfma_f32_16x16x32_bf16(
                        af[mi], bf[ni], acc[mi][ni], 0, 0, 0);
        }
        asm volatile("s_waitcnt lgkmcnt(0)" ::: "memory");
        __builtin_amdgcn_s_barrier();
        cur ^= 1;
    }

    // epilogue: bias(+gelu) -> LDS [64][132] -> coalesced dwordx4
    short* Cs = SH;
    #pragma unroll
    for (int mi = 0; mi < 2; ++mi)
        #pragma unroll
        for (int ni = 0; ni < 4; ++ni) {
            const int cl = wc * 64 + ni * 16 + l15;
            const float bv = bias[n0 + cl];
            #pragma unroll
            for (int r = 0; r < 4; ++r) {
                const int rl = wr * 32 + mi * 16 + lg * 4 + r;
                float v = acc[mi][ni][r] + bv;
                if (ACT) v = gelu_f(v);
                Cs[rl * 132 + cl] = f2bf(v);
            }
        }
    __syncthreads();
    #pragma unroll
    for (int i = 0; i < 4; ++i) {
        const int cid = i * 256 + tid;
        const int rl = cid >> 4, cc = (cid & 15) * 8;
        s16x8 vv = *(const s16x8*)(Cs + rl * 132 + cc);
        *(s16x8*)(Cout + (size_t)(m0 + rl) * N + n0 + cc) = vv;
    }
}

// ---------------- FUSED FF1+gelu+FF2+resid+LN (32-row slab) ----------------
// H never touches HBM. LDS: As 16K | Ws 32K | Hs 32K = 80 KB (2 blocks/CU).
__global__ __launch_bounds__(512) void ffused_k(const short* __restrict__ A,
                                                const short* __restrict__ W1t,
                                                const float* __restrict__ b1,
                                                const short* __restrict__ W2t,
                                                const float* __restrict__ b2,
                                                const float* __restrict__ lng,
                                                const float* __restrict__ lnb,
                                                float* __restrict__ X,
                                                short* __restrict__ Xbo)
{
    __shared__ short As[32 * 256];
    __shared__ short Ws[64 * 256];   // also W2 slices [256][64]; epilogue scratch
    __shared__ short Hs[32 * 512];
    const int tid = threadIdx.x;

    const int nwg = gridDim.x;
    int gid = blockIdx.x;
    {
        const int q = nwg >> 3, r = nwg & 7;
        const int x = gid & 7, idx = gid >> 3;
        gid = (x < r ? x * (q + 1) : r * (q + 1) + (x - r) * q) + idx;
    }
    const int m0 = gid * 32;

    const int wv = tid >> 6, lane = tid & 63;
    const int wr = wv >> 2, wcq = wv & 3;
    const int l15 = lane & 15, lg = lane >> 4;

    // stage A once (32x256)
    #pragma unroll
    for (int i = 0; i < 2; ++i) {
        const int cid = i * 512 + tid;
        const int r = cid >> 5, c = cid & 31;
        gl_lds16(A + (size_t)(m0 + r) * 256 + ((c ^ (r & 7)) * 8), As + cid * 8);
    }

    f32x4 acc2[4];
    #pragma unroll
    for (int j = 0; j < 4; ++j) acc2[j] = (f32x4){0.f, 0.f, 0.f, 0.f};

    for (int h = 0; h < 2; ++h) {
        // ---- FF1: 8 chunks of 64 H-cols -> Hs ----
        for (int nc = 0; nc < 8; ++nc) {
            const int ng = h * 512 + nc * 64;
            __syncthreads();   // prev Ws/Hs users done (+vmcnt drain of A on first)
            #pragma unroll
            for (int i = 0; i < 4; ++i) {
                const int cid = i * 512 + tid;
                const int r = cid >> 5, c = cid & 31;
                gl_lds16(W1t + (size_t)(ng + r) * 256 + ((c ^ (r & 7)) * 8), Ws + cid * 8);
            }
            __syncthreads();

            f32x4 a1 = (f32x4){0.f, 0.f, 0.f, 0.f};
            #pragma unroll
            for (int ks = 0; ks < 8; ++ks) {
                const int row = wr * 16 + l15;
                const int ch = ks * 4 + lg;
                s16x8 af = *(const s16x8*)(As + row * 256 + ((ch ^ (row & 7)) * 8));
                const int col = wcq * 16 + l15;
                s16x8 bf = *(const s16x8*)(Ws + col * 256 + ((ch ^ (col & 7)) * 8));
                a1 = __builtin_amdgcn_mfma_f32_16x16x32_bf16(af, bf, a1, 0, 0, 0);
            }
            const int col = wcq * 16 + l15;
            const float bv = b1[ng + col];
            const int hc = nc * 64 + col;
            #pragma unroll
            for (int r2 = 0; r2 < 4; ++r2) {
                const int row = wr * 16 + lg * 4 + r2;
                Hs[row * 512 + (hc ^ ((row & 7) << 3))] = f2bf(gelu_f(a1[r2] + bv));
            }
        }
        // ---- FF2 partial over this half ----
        for (int kc = 0; kc < 8; ++kc) {
            __syncthreads();   // Hs writes / prev Ws reads done
            const int koff = h * 512 + kc * 64;
            #pragma unroll
            for (int i = 0; i < 4; ++i) {
                const int cid = i * 512 + tid;
                const int r = cid >> 3, c = cid & 7;
                gl_lds16(W2t + (size_t)r * 1024 + koff + ((c ^ (r & 7)) * 8), Ws + cid * 8);
            }
            __syncthreads();
            #pragma unroll
            for (int ks = 0; ks < 2; ++ks) {
                const int row = wr * 16 + l15;
                const int ch = kc * 8 + ks * 4 + lg;
                s16x8 af = *(const s16x8*)(Hs + row * 512 + ((ch ^ (row & 7)) * 8));
                #pragma unroll
                for (int ni = 0; ni < 4; ++ni) {
                    const int n = wcq * 64 + ni * 16 + l15;
                    s16x8 bf = *(const s16x8*)(Ws + n * 64 + (((ks * 4 + lg) ^ (n & 7)) * 8));
                    acc2[ni] = __builtin_amdgcn_mfma_f32_16x16x32_bf16(af, bf, acc2[ni], 0, 0, 0);
                }
            }
        }
    }

    // ---- epilogue: bias2 + resid + LN (red/mrs scratch in Ws) ----
    __syncthreads();
    float* redf = (float*)Ws;          // [32][4][2]
    float* mrsf = redf + 256;          // [32][2]

    float v[4][4];
    #pragma unroll
    for (int ni = 0; ni < 4; ++ni) {
        const int col = wcq * 64 + ni * 16 + l15;
        const float bv = b2[col];
        #pragma unroll
        for (int r = 0; r < 4; ++r) {
            const int row = m0 + wr * 16 + lg * 4 + r;
            v[ni][r] = acc2[ni][r] + bv + X[(size_t)row * 256 + col];
        }
    }
    #pragma unroll
    for (int r = 0; r < 4; ++r) {
        float ss = v[0][r] + v[1][r] + v[2][r] + v[3][r];
        float qq = v[0][r] * v[0][r] + v[1][r] * v[1][r]
                 + v[2][r] * v[2][r] + v[3][r] * v[3][r];
        #pragma unroll
        for (int msk = 1; msk < 16; msk <<= 1) {
            ss += __shfl_xor(ss, msk);
            qq += __shfl_xor(qq, msk);
        }
        if (l15 == 0) {
            const int rl = wr * 16 + lg * 4 + r;
            redf[(rl * 4 + wcq) * 2 + 0] = ss;
            redf[(rl * 4 + wcq) * 2 + 1] = qq;
        }
    }
    __syncthreads();
    if (tid < 32) {
        float s = 0.f, q = 0.f;
        #pragma unroll
        for (int w = 0; w < 4; ++w) { s += redf[(tid * 4 + w) * 2]; q += redf[(tid * 4 + w) * 2 + 1]; }
        const float mean = s * (1.f / 256.f);
        const float var = q * (1.f / 256.f) - mean * mean;
        mrsf[tid * 2 + 0] = mean;
        mrsf[tid * 2 + 1] = rsqrtf(var + 1e-5f);
    }
    __syncthreads();
    #pragma unroll
    for (int ni = 0; ni < 4; ++ni) {
        const int col = wcq * 64 + ni * 16 + l15;
        const float gg = lng[col], bb = lnb[col];
        #pragma unroll
        for (int r = 0; r < 4; ++r) {
            const int rl = wr * 16 + lg * 4 + r;
            const int row = m0 + rl;
            const float o = (v[ni][r] - mrsf[rl * 2]) * mrsf[rl * 2 + 1] * gg + bb;
            X[(size_t)row * 256 + col] = o;
            Xbo[(size_t)row * 256 + col] = f2bf(o);
        }
    }
}

// ---------------- fused GEMM(32x256 full-row) + resid + LayerNorm (Wo) ----------------
__global__ __launch_bounds__(512) void bgemmln_k(const short* __restrict__ A,
                                                 const short* __restrict__ Bt,
                                                 const float* __restrict__ bias,
                                                 const float* __restrict__ lng,
                                                 const float* __restrict__ lnb,
                                                 float* __restrict__ X,
                                                 short* __restrict__ Xb,
                                                 int K)
{
    __shared__ short As[32 * 64];
    __shared__ short Bs[256 * 64];
    __shared__ float red[32][4][2];
    __shared__ float mrs[32][2];
    const int tid = threadIdx.x;

    const int nwg = gridDim.x;
    int gid = blockIdx.x;
    {
        const int q = nwg >> 3, r = nwg & 7;
        const int x = gid & 7, idx = gid >> 3;
        gid = (x < r ? x * (q + 1) : r * (q + 1) + (x - r) * q) + idx;
    }
    const int m0 = gid * 32;

    const int wv = tid >> 6, lane = tid & 63;
    const int wr = wv >> 2, wcx = wv & 3;
    const int l15 = lane & 15, lg = lane >> 4;

    f32x4 acc[4];
    #pragma unroll
    for (int j = 0; j < 4; ++j) acc[j] = (f32x4){0.f, 0.f, 0.f, 0.f};

    const int nt = K >> 6;
    for (int t = 0; t < nt; ++t) {
        __syncthreads();
        const int k0 = t << 6;
        if (tid < 256) {
            const int r = tid >> 3, c = tid & 7;
            gl_lds16(A + (size_t)(m0 + r) * K + k0 + ((c ^ (r & 7)) * 8), As + tid * 8);
        }
        #pragma unroll
        for (int i = 0; i < 4; ++i) {
            const int cid = i * 512 + tid;
            const int r = cid >> 3, c = cid & 7;
            gl_lds16(Bt + (size_t)r * K + k0 + ((c ^ (r & 7)) * 8), Bs + cid * 8);
        }
        __syncthreads();

        #pragma unroll
        for (int ks = 0; ks < 2; ++ks) {
            s16x8 af, bf[4];
            {
                const int row = wr * 16 + l15;
                const int ch = ks * 4 + lg;
                af = *(const s16x8*)(As + row * 64 + ((ch ^ (row & 7)) * 8));
            }
            #pragma unroll
            for (int ni = 0; ni < 4; ++ni) {
                const int col = wcx * 64 + ni * 16 + l15;
                const int ch = ks * 4 + lg;
                bf[ni] = *(const s16x8*)(Bs + col * 64 + ((ch ^ (col & 7)) * 8));
            }
            #pragma unroll
            for (int ni = 0; ni < 4; ++ni)
                acc[ni] = __builtin_amdgcn_mfma_f32_16x16x32_bf16(af, bf[ni], acc[ni], 0, 0, 0);
        }
    }

    float v[4][4];
    #pragma unroll
    for (int ni = 0; ni < 4; ++ni) {
        const int col = wcx * 64 + ni * 16 + l15;
        const float bv = bias[col];
        #pragma unroll
        for (int r = 0; r < 4; ++r) {
            const int row = m0 + wr * 16 + lg * 4 + r;
            v[ni][r] = acc[ni][r] + bv + X[(size_t)row * 256 + col];
        }
    }

    #pragma unroll
    for (int r = 0; r < 4; ++r) {
        float ss = v[0][r] + v[1][r] + v[2][r] + v[3][r];
        float qq = v[0][r] * v[0][r] + v[1][r] * v[1][r]
                 + v[2][r] * v[2][r] + v[3][r] * v[3][r];
        #pragma unroll
        for (int msk = 1; msk < 16; msk <<= 1) {
            ss += __shfl_xor(ss, msk);
            qq += __shfl_xor(qq, msk);
        }
        if (l15 == 0) {
            const int rloc = wr * 16 + lg * 4 + r;
            red[rloc][wcx][0] = ss;
            red[rloc][wcx][1] = qq;
        }
    }
    __syncthreads();
    if (tid < 32) {
        const float s = red[tid][0][0] + red[tid][1][0] + red[tid][2][0] + red[tid][3][0];
        const float q = red[tid][0][1] + red[tid][1][1] + red[tid][2][1] + red[tid][3][1];
        const float mean = s * (1.f / 256.f);
        const float var = q * (1.f / 256.f) - mean * mean;
        mrs[tid][0] = mean;
        mrs[tid][1] = rsqrtf(var + 1e-5f);
    }
    __syncthreads();

    #pragma unroll
    for (int ni = 0; ni < 4; ++ni) {
        const int col = wcx * 64 + ni * 16 + l15;
        const float gg = lng[col], bb = lnb[col];
        #pragma unroll
        for (int r = 0; r < 4; ++r) {
            const int rloc = wr * 16 + lg * 4 + r;
            const int row = m0 + rloc;
            const float o = (v[ni][r] - mrs[rloc][0]) * mrs[rloc][1] * gg + bb;
            X[(size_t)row * 256 + col] = o;
            Xb[(size_t)row * 256 + col] = f2bf(o);
        }
    }
}

// ---------------- MFMA flash attention ----------------
__global__ __launch_bounds__(512) void mattn_k(const short* __restrict__ qkv,
                                               short* __restrict__ o)
{
    int wg = blockIdx.x;
    wg = (wg & 7) * 64 + (wg >> 3);
    const int qt = wg & 3, h = (wg >> 2) & 7, b = wg >> 5;

    const int tid = threadIdx.x, wv = tid >> 6, lane = tid & 63;
    const int q31 = lane & 31, hi = lane >> 5;
    __shared__ short Ks[2][64 * 40];
    __shared__ short VT[2][32 * 72];

    const int q0w = qt * 256 + wv * 32;
    int qrow = q0w + q31; if (qrow > 999) qrow = 999;
    s16x8 bq[2];
    #pragma unroll
    for (int dh = 0; dh < 2; ++dh)
        bq[dh] = *(const s16x8*)(qkv + ((size_t)(b * TT_ + qrow)) * 768 + h * 32 + dh * 16 + hi * 8);

    f32x16 oacc;
    #pragma unroll
    for (int i = 0; i < 16; ++i) oacc[i] = 0.f;
    float lrun = 0.f;

    const int sr = tid >> 2, sc = tid & 3;
    const int u = tid & 255;
    const int kp = u >> 3, dq = (u & 7) * 4;
    s16x8 kreg;
    short4 va, vb;
    auto LOADT = [&](int kt) {
        if (tid < 256) {
            int t = kt * 64 + sr; if (t > 999) t = 999;
            kreg = *(const s16x8*)(qkv + ((size_t)(b * TT_ + t)) * 768 + 256 + h * 32 + sc * 8);
        } else {
            int t0 = kt * 64 + 2 * kp, t1 = t0 + 1;
            if (t0 > 999) t0 = 999;
            if (t1 > 999) t1 = 999;
            va = *(const short4*)(qkv + ((size_t)(b * TT_ + t0)) * 768 + 512 + h * 32 + dq);
            vb = *(const short4*)(qkv + ((size_t)(b * TT_ + t1)) * 768 + 512 + h * 32 + dq);
        }
    };
    auto WRITET = [&](int buf) {
        if (tid < 256) {
            *(s16x8*)(&Ks[buf][sr * 40 + sc * 8]) = kreg;
        } else {
            const int c = kp >> 2;
            const int ko = (2 * kp) & 7;
            const uint2 vaw = *(const uint2*)&va;
            const uint2 vbw = *(const uint2*)&vb;
            unsigned pk[4];
            pk[0] = __builtin_amdgcn_perm(vbw.x, vaw.x, 0x05040100u);
            pk[1] = __builtin_amdgcn_perm(vbw.x, vaw.x, 0x07060302u);
            pk[2] = __builtin_amdgcn_perm(vbw.y, vaw.y, 0x05040100u);
            pk[3] = __builtin_amdgcn_perm(vbw.y, vaw.y, 0x07060302u);
            #pragma unroll
            for (int j = 0; j < 4; ++j) {
                const int d = dq + j;
                *(unsigned*)(&VT[buf][d * 72 + ((c ^ (d >> 3)) * 8) + ko]) = pk[j];
            }
        }
    };

    LOADT(0); WRITET(0);
    __syncthreads();
    int cur = 0;

    for (int kt = 0; kt < 16; ++kt) {
        if (kt < 15) LOADT(kt + 1);

        f32x16 st[2];
        __builtin_amdgcn_s_setprio(1);
        #pragma unroll
        for (int kb = 0; kb < 2; ++kb) {
            s16x8 kf0 = *(const s16x8*)(&Ks[cur][(kb * 32 + q31) * 40 + hi * 8]);
            s16x8 kf1 = *(const s16x8*)(&Ks[cur][(kb * 32 + q31) * 40 + 16 + hi * 8]);
            f32x16 z;
            #pragma unroll
            for (int i = 0; i < 16; ++i) z[i] = 0.f;
            z = __builtin_amdgcn_mfma_f32_32x32x16_bf16(kf0, bq[0], z, 0, 0, 0);
            z = __builtin_amdgcn_mfma_f32_32x32x16_bf16(kf1, bq[1], z, 0, 0, 0);
            st[kb] = z;
        }
        __builtin_amdgcn_s_setprio(0);

        if (kt == 15) {
            #pragma unroll
            for (int kb = 0; kb < 2; ++kb)
                #pragma unroll
                for (int r = 0; r < 16; ++r) {
                    const int kloc = kb * 32 + (r & 3) + 8 * (r >> 2) + 4 * hi;
                    if (960 + kloc >= TT_) st[kb][r] = -1e30f;
                }
        }

        float sloc = 0.f;
        #pragma unroll
        for (int kb = 0; kb < 2; ++kb)
            #pragma unroll
            for (int r = 0; r < 16; ++r) {
                const float p = exp2i(st[kb][r]);
                st[kb][r] = p; sloc += p;
            }
        lrun += sloc;

        unsigned wk[2][4][2];
        #pragma unroll
        for (int kb = 0; kb < 2; ++kb)
            #pragma unroll
            for (int a = 0; a < 4; ++a)
                #pragma unroll
                for (int h2 = 0; h2 < 2; ++h2) {
                    unsigned rr;
                    asm("v_cvt_pk_bf16_f32 %0, %1, %2"
                        : "=v"(rr)
                        : "v"(st[kb][4 * a + 2 * h2]), "v"(st[kb][4 * a + 2 * h2 + 1]));
                    wk[kb][a][h2] = rr;
                }

        #pragma unroll
        for (int ks = 0; ks < 4; ++ks) {
            const int kb = ks >> 1, qq = ks & 1;
            unsigned X0 = wk[kb][2 * qq + 1][0], Y0 = wk[kb][2 * qq][0];
            unsigned X1 = wk[kb][2 * qq + 1][1], Y1 = wk[kb][2 * qq][1];
            asm("v_permlane32_swap_b32 %0, %1" : "+v"(X0), "+v"(Y0));
            asm("v_permlane32_swap_b32 %0, %1" : "+v"(X1), "+v"(Y1));
            u32x4 w4 = (u32x4){Y0, Y1, X0, X1};
            s16x8 pb = __builtin_bit_cast(s16x8, w4);
            s16x8 vf = *(const s16x8*)(&VT[cur][q31 * 72 + (((2 * ks + hi) ^ (q31 >> 3)) * 8)]);
            __builtin_amdgcn_s_setprio(1);
            oacc = __builtin_amdgcn_mfma_f32_32x32x16_bf16(vf, pb, oacc, 0, 0, 0);
            __builtin_amdgcn_s_setprio(0);
        }

        if (kt < 15) WRITET(cur ^ 1);
        __syncthreads();
        cur ^= 1;
    }

    lrun += __shfl_xor(lrun, 32);

    const int t = q0w + q31;
    if (t < TT_) {
        const float inv = 1.f / lrun;
        short* ob = o + ((size_t)(b * TT_ + t)) * 256 + h * 32;
        #pragma unroll
        for (int a = 0; a < 4; ++a) {
            unsigned w0, w1;
            asm("v_cvt_pk_bf16_f32 %0, %1, %2"
                : "=v"(w0) : "v"(oacc[4 * a + 0] * inv), "v"(oacc[4 * a + 1] * inv));
            asm("v_cvt_pk_bf16_f32 %0, %1, %2"
                : "=v"(w1) : "v"(oacc[4 * a + 2] * inv), "v"(oacc[4 * a + 3] * inv));
            const int d0 = 8 * a + 4 * hi;
            *(unsigned*)(ob + d0) = w0;
            *(unsigned*)(ob + d0 + 2) = w1;
        }
    }
}

// ---------------- mean pool ----------------
__global__ __launch_bounds__(256) void pool_part_k(const float* __restrict__ X,
                                                   float* __restrict__ partial)
{
    const int b = blockIdx.x, seg = blockIdx.y, d = threadIdx.x;
    float s = 0.f;
    const int t0 = seg * 125;
    for (int t = t0; t < t0 + 125; ++t) s += X[((size_t)b * TT_ + t) * 256 + d];
    partial[(b * 8 + seg) * 256 + d] = s;
}
__global__ __launch_bounds__(256) void pool_red_k(const float* __restrict__ partial,
                                                  float* __restrict__ pooled)
{
    const int b = blockIdx.x, d = threadIdx.x;
    float s = 0.f;
    for (int k = 0; k < 8; ++k) s += partial[(b * 8 + k) * 256 + d];
    pooled[b * 256 + d] = s * (1.f / (float)TT_);
}

// ---------------- decode head ----------------
__global__ __launch_bounds__(128) void head_k(const float* __restrict__ pooled,
                                              const float* __restrict__ toLW,
                                              const float* __restrict__ toLb,
                                              const float* __restrict__ dW1,
                                              const float* __restrict__ db1,
                                              const float* __restrict__ dW2,
                                              const float* __restrict__ db2,
                                              float* __restrict__ coeffs)
{
    const int b = blockIdx.x, j = threadIdx.x;
    __shared__ float hs[64];
    __shared__ float hid[128];
    float a = toLb[j];
    for (int d = 0; d < 256; ++d) a += pooled[b * 256 + d] * toLW[d * 128 + j];
    if (j < 64) hs[j] = a;
    __syncthreads();
    float a2 = db1[j];
    for (int z = 0; z < 64; ++z) a2 += hs[z] * dW1[z * 128 + j];
    hid[j] = fmaxf(a2, 0.f);
    __syncthreads();
    if (j < 120) {
        float a3 = db2[j];
        for (int k = 0; k < 128; ++k) a3 += hid[k] * dW2[k * 120 + j];
        coeffs[b * 120 + j] = a3;
    }
}

// ---------------- combined conv kernel ----------------
__global__ void comb_k(const float* __restrict__ selfK,
                       const float* __restrict__ cplW,
                       const float* __restrict__ cplB,
                       float* __restrict__ comb)
{
    const int n = threadIdx.x;
    for (int ti = 0; ti < 20; ++ti) {
        float s = selfK[ti * 256 + n];
        #pragma unroll
        for (int si = 0; si < 4; ++si) s += cplW[n * 4 + si] * cplB[ti * 4 + si];
        comb[n * 20 + ti] = s;
    }
}

// ---------------- sti_lat ----------------
__global__ __launch_bounds__(256) void stilat_k(const float* __restrict__ SB,
                                                const float* __restrict__ coeffs,
                                                float* __restrict__ STL)
{
    const int bf = blockIdx.x;
    __shared__ float c[30];
    if (threadIdx.x < 30) c[threadIdx.x] = coeffs[(bf >> 2) * 120 + (bf & 3) * 30 + threadIdx.x];
    __syncthreads();
    for (int t = threadIdx.x; t < TT_; t += 256) {
        float acc = 0.f;
        const float* sp = SB + (size_t)t * 30;
        #pragma unroll
        for (int k = 0; k < 30; ++k) acc += c[k] * sp[k];
        STL[bf * TT_ + t] = acc;
    }
}

// ---------------- final ----------------
__global__ __launch_bounds__(256) void final_k(const float* __restrict__ Y,
                                               const float* __restrict__ STL,
                                               const float* __restrict__ roW,
                                               const float* __restrict__ comb,
                                               float* __restrict__ out)
{
    const int bx = blockIdx.x;
    const int ts = bx & 3, nc = (bx >> 2) & 31, b = bx >> 7;
    const int n0 = nc * 8, t0 = ts * 250;
    const int tid = threadIdx.x;
    __shared__ float rw[8][4], ck[8][20], yl[8][272];

    if (tid < 32) rw[tid >> 2][tid & 3] = roW[(n0 + (tid >> 2)) * 4 + (tid & 3)];
    if (tid >= 64 && tid < 224) {
        const int j = tid - 64;
        ck[j / 20][j % 20] = comb[(n0 + j / 20) * 20 + (j % 20)];
    }
    for (int j = tid; j < 2160; j += 256) {
        const int n = j / 270, jj = j - n * 270;
        yl[n][jj] = Y[((size_t)(b * 256 + n0 + n)) * TTOT_ + t0 + 80 + jj];
    }
    __syncthreads();

    if (tid < 250) {
        const int t = t0 + tid;
        float s4[4];
        #pragma unroll
        for (int f = 0; f < 4; ++f) s4[f] = STL[((size_t)b * 4 + f) * TT_ + t];
        #pragma unroll
        for (int n = 0; n < 8; ++n) {
            float acc = rw[n][0] * s4[0] + rw[n][1] * s4[1]
                      + rw[n][2] * s4[2] + rw[n][3] * s4[3];
            #pragma unroll
            for (int tau = 1; tau <= 20; ++tau)
                acc += ck[n][tau - 1] * yl[n][tid + 20 - tau];
            out[((size_t)(b * 256 + n0 + n)) * TT_ + t] = acc;
        }
    }
}

// ---------------- launch ----------------
extern "C" void kernel_launch(void* const* d_in, const int* in_sizes, int n_in,
                              void* d_out, int out_size, void* d_ws, size_t ws_size,
                              hipStream_t stream)
{
    const float* Y      = (const float*)d_in[0];
    const float* tokW   = (const float*)d_in[1];
    const float* tokb   = (const float*)d_in[2];
    const float* Wqkv   = (const float*)d_in[3];
    const float* bqkv   = (const float*)d_in[4];
    const float* Wo     = (const float*)d_in[5];
    const float* bo     = (const float*)d_in[6];
    const float* ln1g   = (const float*)d_in[7];
    const float* ln1b   = (const float*)d_in[8];
    const float* W1     = (const float*)d_in[9];
    const float* b1     = (const float*)d_in[10];
    const float* W2     = (const float*)d_in[11];
    const float* b2     = (const float*)d_in[12];
    const float* ln2g   = (const float*)d_in[13];
    const float* ln2b   = (const float*)d_in[14];
    const float* toLW   = (const float*)d_in[15];
    const float* toLb   = (const float*)d_in[16];
    const float* dW1    = (const float*)d_in[17];
    const float* db1    = (const float*)d_in[18];
    const float* dW2    = (const float*)d_in[19];
    const float* db2    = (const float*)d_in[20];
    const float* SB     = (const float*)d_in[21];
    const float* roW    = (const float*)d_in[22];
    const float* cplW   = (const float*)d_in[23];
    const float* cplB   = (const float*)d_in[24];
    const float* selfK  = (const float*)d_in[25];

    float* ws  = (float*)d_ws;
    float* X   = ws + X_OFF;
    short* Xb  = (short*)(ws + XB_OFF);
    short* O   = (short*)(ws + O_OFF);
    short* BIG = (short*)(ws + BIG_OFF);
    short* WT  = (short*)(ws + WT_OFF);
    float* PE  = ws + PE_OFF;
    float* PP  = ws + PP_OFF;
    float* PL  = ws + PL_OFF;
    float* CF  = ws + CF_OFF;
    float* CB  = ws + CB_OFF;
    float* BQ  = ws + BQ_OFF;
    float* STL = ws + STL_OFF;

    short* WTqkv = WT;
    short* WTo   = WT + 786432;
    short* WTw1  = WT + 1048576;
    short* WTw2  = WT + 2097152;
    short* WTtok = WT + 3145728;
    short* Ybt   = BIG;

    wtr_k<<<dim3(24, 8, 4), 256, 0, stream>>>(Wqkv, WTqkv, 256, 768, 256, SC2_);
    wtr_k<<<dim3(8, 8, 4),  256, 0, stream>>>(Wo,   WTo,   256, 256, 0, 1.f);
    wtr_k<<<dim3(32, 8, 4), 256, 0, stream>>>(W1,   WTw1,  256, 1024, 0, 1.f);
    wtr_k<<<dim3(8, 32, 4), 256, 0, stream>>>(W2,   WTw2,  1024, 256, 0, 1.f);
    wtr_k<<<dim3(8, 8, 1),  256, 0, stream>>>(tokW, WTtok, 256, 256, 0, 1.f);
    bscale_k<<<12, 256, 0, stream>>>(bqkv, BQ);
    pe_k<<<1000, 256, 0, stream>>>(PE);
    ytr_k<<<dim3(32, 8, 16), 256, 0, stream>>>(Y, Ybt);

    bgemm_k<0, 0, 2, 1><<<500, 256, 0, stream>>>(
        Ybt, WTtok, tokb, PE, X, Xb, 16000, 256, 256, 2);

    for (int l = 0; l < 4; ++l) {
        bgemm_db_k<0><<<1500, 256, 0, stream>>>(
            Xb, WTqkv + (size_t)l * 196608, BQ + l * 768, BIG,
            16000, 768, 256, 6);
        mattn_k<<<512, 512, 0, stream>>>(BIG, O);
        bgemmln_k<<<500, 512, 0, stream>>>(
            O, WTo + (size_t)l * 65536, bo + l * 256,
            ln1g + l * 256, ln1b + l * 256, X, Xb, 256);
        ffused_k<<<500, 512, 0, stream>>>(
            Xb, WTw1 + (size_t)l * 262144, b1 + l * 1024,
            WTw2 + (size_t)l * 262144, b2 + l * 256,
            ln2g + l * 256, ln2b + l * 256, X, Xb);
    }

    pool_part_k<<<dim3(16, 8), 256, 0, stream>>>(X, PP);
    pool_red_k<<<16, 256, 0, stream>>>(PP, PL);
    head_k<<<16, 128, 0, stream>>>(PL, toLW, toLb, dW1, db1, dW2, db2, CF);
    comb_k<<<1, 256, 0, stream>>>(selfK, cplW, cplB, CB);
    stilat_k<<<64, 256, 0, stream>>>(SB, CF, STL);
    final_k<<<2048, 256, 0, stream>>>(Y, STL, roW, CB, (float*)d_out);
}

// Round 16
// 488.183 us; speedup vs baseline: 1.3887x; 1.0208x over previous
//
#include <hip/hip_runtime.h>
#include <math.h>

// ---------------- problem constants ----------------
#define TT_   1000
#define TTOT_ 1100
#define NPAD_ 100
#define DD_   256
#define NN_   256

// workspace layout (float units)
#define X_OFF    0u
#define XB_OFF   4096000u
#define O_OFF    6144000u
#define BIG_OFF  12288000u
#define WT_OFF   20480000u
#define PE_OFF   22085632u
#define PP_OFF   22341632u
#define PL_OFF   (PP_OFF + 32768u)
#define CF_OFF   (PL_OFF + 4096u)
#define CB_OFF   (CF_OFF + 1920u)
#define BQ_OFF   (CF_OFF + 1920u + 5120u)
#define STL_OFF  (BQ_OFF + 3072u)

#define SC2_ 0.25503902254649546f   // (1/sqrt(32)) * log2(e)

typedef __attribute__((ext_vector_type(8))) short s16x8;
typedef __attribute__((ext_vector_type(4))) float f32x4;
typedef __attribute__((ext_vector_type(16))) float f32x16;
typedef __attribute__((ext_vector_type(4))) unsigned u32x4;

__device__ inline short f2bf(float f) {
    unsigned u = __float_as_uint(f);
    u += 0x7fffu + ((u >> 16) & 1u);
    return (short)(u >> 16);
}
__device__ inline float exp2i(float x) {
    float r; asm("v_exp_f32 %0, %1" : "=v"(r) : "v"(x)); return r;
}
// tanh-based GELU (validated: absmax unchanged at 0.0039)
__device__ inline float gelu_f(float v) {
    const float t = v * (0.7978845608f + 0.0356774081f * v * v);
    const float e = exp2i(t * 2.885390082f);
    const float th = 1.f - 2.f / (e + 1.f);
    return 0.5f * v * (1.f + th);
}

__device__ inline void gl_lds16(const short* g, short* l) {
    __builtin_amdgcn_global_load_lds(
        (const __attribute__((address_space(1))) void*)g,
        (__attribute__((address_space(3))) void*)l, 16, 0, 0);
}

// ---------------- weight transpose-convert ----------------
__global__ __launch_bounds__(256) void wtr_k(const float* __restrict__ in,
                                             short* __restrict__ out, int K, int N,
                                             int qrows, float qs)
{
    __shared__ float t[32][33];
    const int n0 = blockIdx.x * 32, k0 = blockIdx.y * 32;
    in  += (size_t)blockIdx.z * K * N;
    out += (size_t)blockIdx.z * K * N;
    const int tx = threadIdx.x & 31, ty = threadIdx.x >> 5;
    #pragma unroll
    for (int i = 0; i < 4; ++i)
        t[ty + 8 * i][tx] = in[(size_t)(k0 + ty + 8 * i) * N + n0 + tx];
    __syncthreads();
    #pragma unroll
    for (int i = 0; i < 4; ++i) {
        const int row = n0 + ty + 8 * i;
        float f = t[tx][ty + 8 * i];
        if (row < qrows) f *= qs;
        out[(size_t)row * K + k0 + tx] = f2bf(f);
    }
}

// ---------------- Y transpose-convert ----------------
__global__ __launch_bounds__(256) void ytr_k(const float* __restrict__ Y,
                                             short* __restrict__ out)
{
    __shared__ float t[32][33];
    const int b = blockIdx.z;
    const int t0 = blockIdx.x * 32, n0 = blockIdx.y * 32;
    const int tx = threadIdx.x & 31, ty = threadIdx.x >> 5;
    #pragma unroll
    for (int i = 0; i < 4; ++i) {
        const int tt = t0 + tx;
        t[ty + 8 * i][tx] = (tt < TT_)
            ? Y[((size_t)(b * NN_ + n0 + ty + 8 * i)) * TTOT_ + NPAD_ + tt] : 0.f;
    }
    __syncthreads();
    #pragma unroll
    for (int i = 0; i < 4; ++i) {
        const int tt = t0 + ty + 8 * i;
        if (tt < TT_)
            out[((size_t)(b * TT_ + tt)) * NN_ + n0 + tx] = f2bf(t[tx][ty + 8 * i]);
    }
}

// ---------------- positional-encoding table ----------------
__global__ void pe_k(float* __restrict__ PE)
{
    const int t = blockIdx.x, d = threadIdx.x;
    const float div = __expf(-(float)(d & ~1) * 0.0269834190585241f);
    const float ang = (float)t * div;
    PE[t * 256 + d] = (d & 1) ? cosf(ang) : sinf(ang);
}

// ---------------- scaled bias copy ----------------
__global__ void bscale_k(const float* __restrict__ in, float* __restrict__ out)
{
    const int i = blockIdx.x * 256 + threadIdx.x;
    if (i < 3072) {
        const int col = i % 768;
        out[i] = in[i] * ((col < 256) ? SC2_ : 1.f);
    }
}

// ---------------- bf16 MFMA GEMM (64x128, single-buffer) — embed only ----------------
template<int OUTBF, int ACT, int RES, int DUAL>
__global__ __launch_bounds__(256) void bgemm_k(const short* __restrict__ A,
                                               const short* __restrict__ Bt,
                                               const float* __restrict__ bias,
                                               const float* __restrict__ resid,
                                               void* __restrict__ Cout,
                                               short* __restrict__ Cb,
                                               int M, int N, int K, int nby)
{
    __shared__ short As[64 * 64];
    __shared__ short Bs[128 * 64];
    const int tid = threadIdx.x;

    const int nwg = gridDim.x;
    int gid = blockIdx.x;
    {
        const int q = nwg >> 3, r = nwg & 7;
        const int x = gid & 7, idx = gid >> 3;
        gid = (x < r ? x * (q + 1) : r * (q + 1) + (x - r) * q) + idx;
    }
    const int bx = gid / nby, by = gid - bx * nby;
    const int m0 = bx * 64, n0 = by * 128;

    const int wv = tid >> 6, lane = tid & 63;
    const int wr = wv >> 1, wc = wv & 1;
    const int l15 = lane & 15, lg = lane >> 4;

    f32x4 acc[2][4];
    #pragma unroll
    for (int i = 0; i < 2; ++i)
        #pragma unroll
        for (int j = 0; j < 4; ++j) acc[i][j] = (f32x4){0.f, 0.f, 0.f, 0.f};

    const int nt = K >> 6;
    for (int t = 0; t < nt; ++t) {
        __syncthreads();
        const int k0 = t << 6;
        #pragma unroll
        for (int i = 0; i < 2; ++i) {
            const int cid = i * 256 + tid;
            const int r = cid >> 3, c = cid & 7;
            gl_lds16(A + (size_t)(m0 + r) * K + k0 + ((c ^ (r & 7)) * 8), As + cid * 8);
        }
        #pragma unroll
        for (int i = 0; i < 4; ++i) {
            const int cid = i * 256 + tid;
            const int r = cid >> 3, c = cid & 7;
            gl_lds16(Bt + (size_t)(n0 + r) * K + k0 + ((c ^ (r & 7)) * 8), Bs + cid * 8);
        }
        __syncthreads();

        #pragma unroll
        for (int ks = 0; ks < 2; ++ks) {
            s16x8 af[2], bf[4];
            #pragma unroll
            for (int mi = 0; mi < 2; ++mi) {
                const int row = wr * 32 + mi * 16 + l15;
                const int ch = ks * 4 + lg;
                af[mi] = *(const s16x8*)(As + row * 64 + ((ch ^ (row & 7)) * 8));
            }
            #pragma unroll
            for (int ni = 0; ni < 4; ++ni) {
                const int col = wc * 64 + ni * 16 + l15;
                const int ch = ks * 4 + lg;
                bf[ni] = *(const s16x8*)(Bs + col * 64 + ((ch ^ (col & 7)) * 8));
            }
            #pragma unroll
            for (int mi = 0; mi < 2; ++mi)
                #pragma unroll
                for (int ni = 0; ni < 4; ++ni)
                    acc[mi][ni] = __builtin_amdgcn_mfma_f32_16x16x32_bf16(
                        af[mi], bf[ni], acc[mi][ni], 0, 0, 0);
        }
    }

    #pragma unroll
    for (int mi = 0; mi < 2; ++mi) {
        #pragma unroll
        for (int ni = 0; ni < 4; ++ni) {
            const int col = n0 + wc * 64 + ni * 16 + l15;
            const float bv = bias[col];
            #pragma unroll
            for (int r = 0; r < 4; ++r) {
                const int row = m0 + wr * 32 + mi * 16 + lg * 4 + r;
                float v = acc[mi][ni][r] + bv;
                if (RES == 1) v += resid[(size_t)row * N + col];
                if (RES == 2) v += resid[(size_t)(row % 1000) * N + col];
                if (ACT) v = gelu_f(v);
                if (OUTBF) ((short*)Cout)[(size_t)row * N + col] = f2bf(v);
                else       ((float*)Cout)[(size_t)row * N + col] = v;
                if (DUAL)  Cb[(size_t)row * N + col] = f2bf(v);
            }
        }
    }
}

// ---------------- bf16 MFMA GEMM (64x128, dbuf, counted vmcnt) — qkv / FF1 ----------------
// COAL=0: direct stores (qkv). COAL=1: LDS-coalesced stores + gelu (FF1).
template<int ACT, int COAL>
__global__ __launch_bounds__(256) void bgemm_db_k(const short* __restrict__ A,
                                                  const short* __restrict__ Bt,
                                                  const float* __restrict__ bias,
                                                  short* __restrict__ Cout,
                                                  int M, int N, int K, int nby)
{
    __shared__ short SH[2 * 12288];
    const int tid = threadIdx.x;

    const int nwg = gridDim.x;
    int gid = blockIdx.x;
    {
        const int q = nwg >> 3, r = nwg & 7;
        const int x = gid & 7, idx = gid >> 3;
        gid = (x < r ? x * (q + 1) : r * (q + 1) + (x - r) * q) + idx;
    }
    const int bx = gid / nby, by = gid - bx * nby;
    const int m0 = bx * 64, n0 = by * 128;

    const int wv = tid >> 6, lane = tid & 63;
    const int wr = wv >> 1, wc = wv & 1;
    const int l15 = lane & 15, lg = lane >> 4;

    f32x4 acc[2][4];
    #pragma unroll
    for (int i = 0; i < 2; ++i)
        #pragma unroll
        for (int j = 0; j < 4; ++j) acc[i][j] = (f32x4){0.f, 0.f, 0.f, 0.f};

    auto STAGE = [&](int p, int k0) {
        short* dA = SH + p * 12288;
        short* dB = dA + 4096;
        #pragma unroll
        for (int i = 0; i < 2; ++i) {
            const int cid = i * 256 + tid;
            const int r = cid >> 3, c = cid & 7;
            gl_lds16(A + (size_t)(m0 + r) * K + k0 + ((c ^ (r & 7)) * 8), dA + cid * 8);
        }
        #pragma unroll
        for (int i = 0; i < 4; ++i) {
            const int cid = i * 256 + tid;
            const int r = cid >> 3, c = cid & 7;
            gl_lds16(Bt + (size_t)(n0 + r) * K + k0 + ((c ^ (r & 7)) * 8), dB + cid * 8);
        }
    };

    const int nt = K >> 6;
    STAGE(0, 0);
    int cur = 0;
    for (int t = 0; t < nt; ++t) {
        if (t + 1 < nt) {
            STAGE(cur ^ 1, (t + 1) << 6);
            asm volatile("s_waitcnt vmcnt(6)" ::: "memory");
        } else {
            asm volatile("s_waitcnt vmcnt(0)" ::: "memory");
        }
        __builtin_amdgcn_s_barrier();

        const short* Asb = SH + cur * 12288;
        const short* Bsb = Asb + 4096;
        #pragma unroll
        for (int ks = 0; ks < 2; ++ks) {
            s16x8 af[2], bf[4];
            #pragma unroll
            for (int mi = 0; mi < 2; ++mi) {
                const int row = wr * 32 + mi * 16 + l15;
                const int ch = ks * 4 + lg;
                af[mi] = *(const s16x8*)(Asb + row * 64 + ((ch ^ (row & 7)) * 8));
            }
            #pragma unroll
            for (int ni = 0; ni < 4; ++ni) {
                const int col = wc * 64 + ni * 16 + l15;
                const int ch = ks * 4 + lg;
                bf[ni] = *(const s16x8*)(Bsb + col * 64 + ((ch ^ (col & 7)) * 8));
            }
            #pragma unroll
            for (int mi = 0; mi < 2; ++mi)
                #pragma unroll
                for (int ni = 0; ni < 4; ++ni)
                    acc[mi][ni] = __builtin_amdgcn_mfma_f32_16x16x32_bf16(
                        af[mi], bf[ni], acc[mi][ni], 0, 0, 0);
        }
        asm volatile("s_waitcnt lgkmcnt(0)" ::: "memory");
        __builtin_amdgcn_s_barrier();
        cur ^= 1;
    }

    if (COAL) {
        // bias(+gelu) -> LDS [64][132] -> coalesced dwordx4
        short* Cs = SH;
        #pragma unroll
        for (int mi = 0; mi < 2; ++mi)
            #pragma unroll
            for (int ni = 0; ni < 4; ++ni) {
                const int cl = wc * 64 + ni * 16 + l15;
                const float bv = bias[n0 + cl];
                #pragma unroll
                for (int r = 0; r < 4; ++r) {
                    const int rl = wr * 32 + mi * 16 + lg * 4 + r;
                    float v = acc[mi][ni][r] + bv;
                    if (ACT) v = gelu_f(v);
                    Cs[rl * 132 + cl] = f2bf(v);
                }
            }
        __syncthreads();
        #pragma unroll
        for (int i = 0; i < 4; ++i) {
            const int cid = i * 256 + tid;
            const int rl = cid >> 4, cc = (cid & 15) * 8;
            s16x8 vv = *(const s16x8*)(Cs + rl * 132 + cc);
            *(s16x8*)(Cout + (size_t)(m0 + rl) * N + n0 + cc) = vv;
        }
    } else {
        #pragma unroll
        for (int mi = 0; mi < 2; ++mi)
            #pragma unroll
            for (int ni = 0; ni < 4; ++ni) {
                const int col = n0 + wc * 64 + ni * 16 + l15;
                const float bv = bias[col];
                #pragma unroll
                for (int r = 0; r < 4; ++r) {
                    const int row = m0 + wr * 32 + mi * 16 + lg * 4 + r;
                    float v = acc[mi][ni][r] + bv;
                    if (ACT) v = gelu_f(v);
                    Cout[(size_t)row * N + col] = f2bf(v);
                }
            }
    }
}

// ---------------- fused GEMM(32x256 full-row) + resid + LayerNorm ----------------
__global__ __launch_bounds__(512) void bgemmln_k(const short* __restrict__ A,
                                                 const short* __restrict__ Bt,
                                                 const float* __restrict__ bias,
                                                 const float* __restrict__ lng,
                                                 const float* __restrict__ lnb,
                                                 float* __restrict__ X,
                                                 short* __restrict__ Xb,
                                                 int K)
{
    __shared__ short As[32 * 64];
    __shared__ short Bs[256 * 64];
    __shared__ float red[32][4][2];
    __shared__ float mrs[32][2];
    const int tid = threadIdx.x;

    const int nwg = gridDim.x;
    int gid = blockIdx.x;
    {
        const int q = nwg >> 3, r = nwg & 7;
        const int x = gid & 7, idx = gid >> 3;
        gid = (x < r ? x * (q + 1) : r * (q + 1) + (x - r) * q) + idx;
    }
    const int m0 = gid * 32;

    const int wv = tid >> 6, lane = tid & 63;
    const int wr = wv >> 2, wcx = wv & 3;
    const int l15 = lane & 15, lg = lane >> 4;

    f32x4 acc[4];
    #pragma unroll
    for (int j = 0; j < 4; ++j) acc[j] = (f32x4){0.f, 0.f, 0.f, 0.f};

    const int nt = K >> 6;
    for (int t = 0; t < nt; ++t) {
        __syncthreads();
        const int k0 = t << 6;
        if (tid < 256) {
            const int r = tid >> 3, c = tid & 7;
            gl_lds16(A + (size_t)(m0 + r) * K + k0 + ((c ^ (r & 7)) * 8), As + tid * 8);
        }
        #pragma unroll
        for (int i = 0; i < 4; ++i) {
            const int cid = i * 512 + tid;
            const int r = cid >> 3, c = cid & 7;
            gl_lds16(Bt + (size_t)r * K + k0 + ((c ^ (r & 7)) * 8), Bs + cid * 8);
        }
        __syncthreads();

        #pragma unroll
        for (int ks = 0; ks < 2; ++ks) {
            s16x8 af, bf[4];
            {
                const int row = wr * 16 + l15;
                const int ch = ks * 4 + lg;
                af = *(const s16x8*)(As + row * 64 + ((ch ^ (row & 7)) * 8));
            }
            #pragma unroll
            for (int ni = 0; ni < 4; ++ni) {
                const int col = wcx * 64 + ni * 16 + l15;
                const int ch = ks * 4 + lg;
                bf[ni] = *(const s16x8*)(Bs + col * 64 + ((ch ^ (col & 7)) * 8));
            }
            #pragma unroll
            for (int ni = 0; ni < 4; ++ni)
                acc[ni] = __builtin_amdgcn_mfma_f32_16x16x32_bf16(af, bf[ni], acc[ni], 0, 0, 0);
        }
    }

    float v[4][4];
    #pragma unroll
    for (int ni = 0; ni < 4; ++ni) {
        const int col = wcx * 64 + ni * 16 + l15;
        const float bv = bias[col];
        #pragma unroll
        for (int r = 0; r < 4; ++r) {
            const int row = m0 + wr * 16 + lg * 4 + r;
            v[ni][r] = acc[ni][r] + bv + X[(size_t)row * 256 + col];
        }
    }

    #pragma unroll
    for (int r = 0; r < 4; ++r) {
        float ss = v[0][r] + v[1][r] + v[2][r] + v[3][r];
        float qq = v[0][r] * v[0][r] + v[1][r] * v[1][r]
                 + v[2][r] * v[2][r] + v[3][r] * v[3][r];
        #pragma unroll
        for (int msk = 1; msk < 16; msk <<= 1) {
            ss += __shfl_xor(ss, msk);
            qq += __shfl_xor(qq, msk);
        }
        if (l15 == 0) {
            const int rloc = wr * 16 + lg * 4 + r;
            red[rloc][wcx][0] = ss;
            red[rloc][wcx][1] = qq;
        }
    }
    __syncthreads();
    if (tid < 32) {
        const float s = red[tid][0][0] + red[tid][1][0] + red[tid][2][0] + red[tid][3][0];
        const float q = red[tid][0][1] + red[tid][1][1] + red[tid][2][1] + red[tid][3][1];
        const float mean = s * (1.f / 256.f);
        const float var = q * (1.f / 256.f) - mean * mean;
        mrs[tid][0] = mean;
        mrs[tid][1] = rsqrtf(var + 1e-5f);
    }
    __syncthreads();

    #pragma unroll
    for (int ni = 0; ni < 4; ++ni) {
        const int col = wcx * 64 + ni * 16 + l15;
        const float gg = lng[col], bb = lnb[col];
        #pragma unroll
        for (int r = 0; r < 4; ++r) {
            const int rloc = wr * 16 + lg * 4 + r;
            const int row = m0 + rloc;
            const float o = (v[ni][r] - mrs[rloc][0]) * mrs[rloc][1] * gg + bb;
            X[(size_t)row * 256 + col] = o;
            Xb[(size_t)row * 256 + col] = f2bf(o);
        }
    }
}

// ---------------- MFMA flash attention ----------------
__global__ __launch_bounds__(512) void mattn_k(const short* __restrict__ qkv,
                                               short* __restrict__ o)
{
    int wg = blockIdx.x;
    wg = (wg & 7) * 64 + (wg >> 3);
    const int qt = wg & 3, h = (wg >> 2) & 7, b = wg >> 5;

    const int tid = threadIdx.x, wv = tid >> 6, lane = tid & 63;
    const int q31 = lane & 31, hi = lane >> 5;
    __shared__ short Ks[2][64 * 40];
    __shared__ short VT[2][32 * 72];

    const int q0w = qt * 256 + wv * 32;
    int qrow = q0w + q31; if (qrow > 999) qrow = 999;
    s16x8 bq[2];
    #pragma unroll
    for (int dh = 0; dh < 2; ++dh)
        bq[dh] = *(const s16x8*)(qkv + ((size_t)(b * TT_ + qrow)) * 768 + h * 32 + dh * 16 + hi * 8);

    f32x16 oacc;
    #pragma unroll
    for (int i = 0; i < 16; ++i) oacc[i] = 0.f;
    float lrun = 0.f;

    const int sr = tid >> 2, sc = tid & 3;
    const int u = tid & 255;
    const int kp = u >> 3, dq = (u & 7) * 4;
    s16x8 kreg;
    short4 va, vb;
    auto LOADT = [&](int kt) {
        if (tid < 256) {
            int t = kt * 64 + sr; if (t > 999) t = 999;
            kreg = *(const s16x8*)(qkv + ((size_t)(b * TT_ + t)) * 768 + 256 + h * 32 + sc * 8);
        } else {
            int t0 = kt * 64 + 2 * kp, t1 = t0 + 1;
            if (t0 > 999) t0 = 999;
            if (t1 > 999) t1 = 999;
            va = *(const short4*)(qkv + ((size_t)(b * TT_ + t0)) * 768 + 512 + h * 32 + dq);
            vb = *(const short4*)(qkv + ((size_t)(b * TT_ + t1)) * 768 + 512 + h * 32 + dq);
        }
    };
    auto WRITET = [&](int buf) {
        if (tid < 256) {
            *(s16x8*)(&Ks[buf][sr * 40 + sc * 8]) = kreg;
        } else {
            const int c = kp >> 2;
            const int ko = (2 * kp) & 7;
            const uint2 vaw = *(const uint2*)&va;
            const uint2 vbw = *(const uint2*)&vb;
            unsigned pk[4];
            pk[0] = __builtin_amdgcn_perm(vbw.x, vaw.x, 0x05040100u);
            pk[1] = __builtin_amdgcn_perm(vbw.x, vaw.x, 0x07060302u);
            pk[2] = __builtin_amdgcn_perm(vbw.y, vaw.y, 0x05040100u);
            pk[3] = __builtin_amdgcn_perm(vbw.y, vaw.y, 0x07060302u);
            #pragma unroll
            for (int j = 0; j < 4; ++j) {
                const int d = dq + j;
                *(unsigned*)(&VT[buf][d * 72 + ((c ^ (d >> 3)) * 8) + ko]) = pk[j];
            }
        }
    };

    LOADT(0); WRITET(0);
    __syncthreads();
    int cur = 0;

    for (int kt = 0; kt < 16; ++kt) {
        if (kt < 15) LOADT(kt + 1);

        f32x16 st[2];
        __builtin_amdgcn_s_setprio(1);
        #pragma unroll
        for (int kb = 0; kb < 2; ++kb) {
            s16x8 kf0 = *(const s16x8*)(&Ks[cur][(kb * 32 + q31) * 40 + hi * 8]);
            s16x8 kf1 = *(const s16x8*)(&Ks[cur][(kb * 32 + q31) * 40 + 16 + hi * 8]);
            f32x16 z;
            #pragma unroll
            for (int i = 0; i < 16; ++i) z[i] = 0.f;
            z = __builtin_amdgcn_mfma_f32_32x32x16_bf16(kf0, bq[0], z, 0, 0, 0);
            z = __builtin_amdgcn_mfma_f32_32x32x16_bf16(kf1, bq[1], z, 0, 0, 0);
            st[kb] = z;
        }
        __builtin_amdgcn_s_setprio(0);

        if (kt == 15) {
            #pragma unroll
            for (int kb = 0; kb < 2; ++kb)
                #pragma unroll
                for (int r = 0; r < 16; ++r) {
                    const int kloc = kb * 32 + (r & 3) + 8 * (r >> 2) + 4 * hi;
                    if (960 + kloc >= TT_) st[kb][r] = -1e30f;
                }
        }

        float sloc = 0.f;
        #pragma unroll
        for (int kb = 0; kb < 2; ++kb)
            #pragma unroll
            for (int r = 0; r < 16; ++r) {
                const float p = exp2i(st[kb][r]);
                st[kb][r] = p; sloc += p;
            }
        lrun += sloc;

        unsigned wk[2][4][2];
        #pragma unroll
        for (int kb = 0; kb < 2; ++kb)
            #pragma unroll
            for (int a = 0; a < 4; ++a)
                #pragma unroll
                for (int h2 = 0; h2 < 2; ++h2) {
                    unsigned rr;
                    asm("v_cvt_pk_bf16_f32 %0, %1, %2"
                        : "=v"(rr)
                        : "v"(st[kb][4 * a + 2 * h2]), "v"(st[kb][4 * a + 2 * h2 + 1]));
                    wk[kb][a][h2] = rr;
                }

        #pragma unroll
        for (int ks = 0; ks < 4; ++ks) {
            const int kb = ks >> 1, qq = ks & 1;
            unsigned X0 = wk[kb][2 * qq + 1][0], Y0 = wk[kb][2 * qq][0];
            unsigned X1 = wk[kb][2 * qq + 1][1], Y1 = wk[kb][2 * qq][1];
            asm("v_permlane32_swap_b32 %0, %1" : "+v"(X0), "+v"(Y0));
            asm("v_permlane32_swap_b32 %0, %1" : "+v"(X1), "+v"(Y1));
            u32x4 w4 = (u32x4){Y0, Y1, X0, X1};
            s16x8 pb = __builtin_bit_cast(s16x8, w4);
            s16x8 vf = *(const s16x8*)(&VT[cur][q31 * 72 + (((2 * ks + hi) ^ (q31 >> 3)) * 8)]);
            __builtin_amdgcn_s_setprio(1);
            oacc = __builtin_amdgcn_mfma_f32_32x32x16_bf16(vf, pb, oacc, 0, 0, 0);
            __builtin_amdgcn_s_setprio(0);
        }

        if (kt < 15) WRITET(cur ^ 1);
        __syncthreads();
        cur ^= 1;
    }

    lrun += __shfl_xor(lrun, 32);

    const int t = q0w + q31;
    if (t < TT_) {
        const float inv = 1.f / lrun;
        short* ob = o + ((size_t)(b * TT_ + t)) * 256 + h * 32;
        #pragma unroll
        for (int a = 0; a < 4; ++a) {
            unsigned w0, w1;
            asm("v_cvt_pk_bf16_f32 %0, %1, %2"
                : "=v"(w0) : "v"(oacc[4 * a + 0] * inv), "v"(oacc[4 * a + 1] * inv));
            asm("v_cvt_pk_bf16_f32 %0, %1, %2"
                : "=v"(w1) : "v"(oacc[4 * a + 2] * inv), "v"(oacc[4 * a + 3] * inv));
            const int d0 = 8 * a + 4 * hi;
            *(unsigned*)(ob + d0) = w0;
            *(unsigned*)(ob + d0 + 2) = w1;
        }
    }
}

// ---------------- mean pool ----------------
__global__ __launch_bounds__(256) void pool_part_k(const float* __restrict__ X,
                                                   float* __restrict__ partial)
{
    const int b = blockIdx.x, seg = blockIdx.y, d = threadIdx.x;
    float s = 0.f;
    const int t0 = seg * 125;
    for (int t = t0; t < t0 + 125; ++t) s += X[((size_t)b * TT_ + t) * 256 + d];
    partial[(b * 8 + seg) * 256 + d] = s;
}
__global__ __launch_bounds__(256) void pool_red_k(const float* __restrict__ partial,
                                                  float* __restrict__ pooled)
{
    const int b = blockIdx.x, d = threadIdx.x;
    float s = 0.f;
    for (int k = 0; k < 8; ++k) s += partial[(b * 8 + k) * 256 + d];
    pooled[b * 256 + d] = s * (1.f / (float)TT_);
}

// ---------------- decode head ----------------
__global__ __launch_bounds__(128) void head_k(const float* __restrict__ pooled,
                                              const float* __restrict__ toLW,
                                              const float* __restrict__ toLb,
                                              const float* __restrict__ dW1,
                                              const float* __restrict__ db1,
                                              const float* __restrict__ dW2,
                                              const float* __restrict__ db2,
                                              float* __restrict__ coeffs)
{
    const int b = blockIdx.x, j = threadIdx.x;
    __shared__ float hs[64];
    __shared__ float hid[128];
    float a = toLb[j];
    for (int d = 0; d < 256; ++d) a += pooled[b * 256 + d] * toLW[d * 128 + j];
    if (j < 64) hs[j] = a;
    __syncthreads();
    float a2 = db1[j];
    for (int z = 0; z < 64; ++z) a2 += hs[z] * dW1[z * 128 + j];
    hid[j] = fmaxf(a2, 0.f);
    __syncthreads();
    if (j < 120) {
        float a3 = db2[j];
        for (int k = 0; k < 128; ++k) a3 += hid[k] * dW2[k * 120 + j];
        coeffs[b * 120 + j] = a3;
    }
}

// ---------------- combined conv kernel ----------------
__global__ void comb_k(const float* __restrict__ selfK,
                       const float* __restrict__ cplW,
                       const float* __restrict__ cplB,
                       float* __restrict__ comb)
{
    const int n = threadIdx.x;
    for (int ti = 0; ti < 20; ++ti) {
        float s = selfK[ti * 256 + n];
        #pragma unroll
        for (int si = 0; si < 4; ++si) s += cplW[n * 4 + si] * cplB[ti * 4 + si];
        comb[n * 20 + ti] = s;
    }
}

// ---------------- sti_lat ----------------
__global__ __launch_bounds__(256) void stilat_k(const float* __restrict__ SB,
                                                const float* __restrict__ coeffs,
                                                float* __restrict__ STL)
{
    const int bf = blockIdx.x;
    __shared__ float c[30];
    if (threadIdx.x < 30) c[threadIdx.x] = coeffs[(bf >> 2) * 120 + (bf & 3) * 30 + threadIdx.x];
    __syncthreads();
    for (int t = threadIdx.x; t < TT_; t += 256) {
        float acc = 0.f;
        const float* sp = SB + (size_t)t * 30;
        #pragma unroll
        for (int k = 0; k < 30; ++k) acc += c[k] * sp[k];
        STL[bf * TT_ + t] = acc;
    }
}

// ---------------- final ----------------
__global__ __launch_bounds__(256) void final_k(const float* __restrict__ Y,
                                               const float* __restrict__ STL,
                                               const float* __restrict__ roW,
                                               const float* __restrict__ comb,
                                               float* __restrict__ out)
{
    const int bx = blockIdx.x;
    const int ts = bx & 3, nc = (bx >> 2) & 31, b = bx >> 7;
    const int n0 = nc * 8, t0 = ts * 250;
    const int tid = threadIdx.x;
    __shared__ float rw[8][4], ck[8][20], yl[8][272];

    if (tid < 32) rw[tid >> 2][tid & 3] = roW[(n0 + (tid >> 2)) * 4 + (tid & 3)];
    if (tid >= 64 && tid < 224) {
        const int j = tid - 64;
        ck[j / 20][j % 20] = comb[(n0 + j / 20) * 20 + (j % 20)];
    }
    for (int j = tid; j < 2160; j += 256) {
        const int n = j / 270, jj = j - n * 270;
        yl[n][jj] = Y[((size_t)(b * 256 + n0 + n)) * TTOT_ + t0 + 80 + jj];
    }
    __syncthreads();

    if (tid < 250) {
        const int t = t0 + tid;
        float s4[4];
        #pragma unroll
        for (int f = 0; f < 4; ++f) s4[f] = STL[((size_t)b * 4 + f) * TT_ + t];
        #pragma unroll
        for (int n = 0; n < 8; ++n) {
            float acc = rw[n][0] * s4[0] + rw[n][1] * s4[1]
                      + rw[n][2] * s4[2] + rw[n][3] * s4[3];
            #pragma unroll
            for (int tau = 1; tau <= 20; ++tau)
                acc += ck[n][tau - 1] * yl[n][tid + 20 - tau];
            out[((size_t)(b * 256 + n0 + n)) * TT_ + t] = acc;
        }
    }
}

// ---------------- launch ----------------
extern "C" void kernel_launch(void* const* d_in, const int* in_sizes, int n_in,
                              void* d_out, int out_size, void* d_ws, size_t ws_size,
                              hipStream_t stream)
{
    const float* Y      = (const float*)d_in[0];
    const float* tokW   = (const float*)d_in[1];
    const float* tokb   = (const float*)d_in[2];
    const float* Wqkv   = (const float*)d_in[3];
    const float* bqkv   = (const float*)d_in[4];
    const float* Wo     = (const float*)d_in[5];
    const float* bo     = (const float*)d_in[6];
    const float* ln1g   = (const float*)d_in[7];
    const float* ln1b   = (const float*)d_in[8];
    const float* W1     = (const float*)d_in[9];
    const float* b1     = (const float*)d_in[10];
    const float* W2     = (const float*)d_in[11];
    const float* b2     = (const float*)d_in[12];
    const float* ln2g   = (const float*)d_in[13];
    const float* ln2b   = (const float*)d_in[14];
    const float* toLW   = (const float*)d_in[15];
    const float* toLb   = (const float*)d_in[16];
    const float* dW1    = (const float*)d_in[17];
    const float* db1    = (const float*)d_in[18];
    const float* dW2    = (const float*)d_in[19];
    const float* db2    = (const float*)d_in[20];
    const float* SB     = (const float*)d_in[21];
    const float* roW    = (const float*)d_in[22];
    const float* cplW   = (const float*)d_in[23];
    const float* cplB   = (const float*)d_in[24];
    const float* selfK  = (const float*)d_in[25];

    float* ws  = (float*)d_ws;
    float* X   = ws + X_OFF;
    short* Xb  = (short*)(ws + XB_OFF);
    short* O   = (short*)(ws + O_OFF);
    short* BIG = (short*)(ws + BIG_OFF);
    short* WT  = (short*)(ws + WT_OFF);
    float* PE  = ws + PE_OFF;
    float* PP  = ws + PP_OFF;
    float* PL  = ws + PL_OFF;
    float* CF  = ws + CF_OFF;
    float* CB  = ws + CB_OFF;
    float* BQ  = ws + BQ_OFF;
    float* STL = ws + STL_OFF;

    short* WTqkv = WT;
    short* WTo   = WT + 786432;
    short* WTw1  = WT + 1048576;
    short* WTw2  = WT + 2097152;
    short* WTtok = WT + 3145728;
    short* Ybt   = BIG;

    wtr_k<<<dim3(24, 8, 4), 256, 0, stream>>>(Wqkv, WTqkv, 256, 768, 256, SC2_);
    wtr_k<<<dim3(8, 8, 4),  256, 0, stream>>>(Wo,   WTo,   256, 256, 0, 1.f);
    wtr_k<<<dim3(32, 8, 4), 256, 0, stream>>>(W1,   WTw1,  256, 1024, 0, 1.f);
    wtr_k<<<dim3(8, 32, 4), 256, 0, stream>>>(W2,   WTw2,  1024, 256, 0, 1.f);
    wtr_k<<<dim3(8, 8, 1),  256, 0, stream>>>(tokW, WTtok, 256, 256, 0, 1.f);
    bscale_k<<<12, 256, 0, stream>>>(bqkv, BQ);
    pe_k<<<1000, 256, 0, stream>>>(PE);
    ytr_k<<<dim3(32, 8, 16), 256, 0, stream>>>(Y, Ybt);

    bgemm_k<0, 0, 2, 1><<<500, 256, 0, stream>>>(
        Ybt, WTtok, tokb, PE, X, Xb, 16000, 256, 256, 2);

    for (int l = 0; l < 4; ++l) {
        bgemm_db_k<0, 0><<<1500, 256, 0, stream>>>(
            Xb, WTqkv + (size_t)l * 196608, BQ + l * 768, BIG,
            16000, 768, 256, 6);
        mattn_k<<<512, 512, 0, stream>>>(BIG, O);
        bgemmln_k<<<500, 512, 0, stream>>>(
            O, WTo + (size_t)l * 65536, bo + l * 256,
            ln1g + l * 256, ln1b + l * 256, X, Xb, 256);
        bgemm_db_k<1, 1><<<2000, 256, 0, stream>>>(
            Xb, WTw1 + (size_t)l * 262144, b1 + l * 1024, BIG,
            16000, 1024, 256, 8);
        bgemmln_k<<<500, 512, 0, stream>>>(
            BIG, WTw2 + (size_t)l * 262144, b2 + l * 256,
            ln2g + l * 256, ln2b + l * 256, X, Xb, 1024);
    }

    pool_part_k<<<dim3(16, 8), 256, 0, stream>>>(X, PP);
    pool_red_k<<<16, 256, 0, stream>>>(PP, PL);
    head_k<<<16, 128, 0, stream>>>(PL, toLW, toLb, dW1, db1, dW2, db2, CF);
    comb_k<<<1, 256, 0, stream>>>(selfK, cplW, cplB, CB);
    stilat_k<<<64, 256, 0, stream>>>(SB, CF, STL);
    final_k<<<2048, 256, 0, stream>>>(Y, STL, roW, CB, (float*)d_out);
}

// Round 17
// 467.769 us; speedup vs baseline: 1.4493x; 1.0436x over previous
//
#include <hip/hip_runtime.h>
#include <math.h>

// ---------------- problem constants ----------------
#define TT_   1000
#define TTOT_ 1100
#define NPAD_ 100
#define DD_   256
#define NN_   256

// workspace layout (float units)
#define X_OFF    0u            // (unused now)
#define XB_OFF   4096000u      // bf16 residual stream 16000x256
#define O_OFF    6144000u
#define BIG_OFF  12288000u
#define WT_OFF   20480000u
#define PE_OFF   22085632u
#define PP_OFF   22341632u
#define PL_OFF   (PP_OFF + 32768u)
#define CF_OFF   (PL_OFF + 4096u)
#define CB_OFF   (CF_OFF + 1920u)
#define BQ_OFF   (CF_OFF + 1920u + 5120u)
#define STL_OFF  (BQ_OFF + 3072u)

#define SC2_ 0.25503902254649546f   // (1/sqrt(32)) * log2(e)

typedef __attribute__((ext_vector_type(8))) short s16x8;
typedef __attribute__((ext_vector_type(4))) float f32x4;
typedef __attribute__((ext_vector_type(16))) float f32x16;
typedef __attribute__((ext_vector_type(4))) unsigned u32x4;

__device__ inline short f2bf(float f) {
    unsigned u = __float_as_uint(f);
    u += 0x7fffu + ((u >> 16) & 1u);
    return (short)(u >> 16);
}
__device__ inline float bf2f(short s) {
    return __uint_as_float(((unsigned)(unsigned short)s) << 16);
}
__device__ inline float exp2i(float x) {
    float r; asm("v_exp_f32 %0, %1" : "=v"(r) : "v"(x)); return r;
}
// tanh-based GELU (validated: absmax unchanged at 0.0039)
__device__ inline float gelu_f(float v) {
    const float t = v * (0.7978845608f + 0.0356774081f * v * v);
    const float e = exp2i(t * 2.885390082f);
    const float th = 1.f - 2.f / (e + 1.f);
    return 0.5f * v * (1.f + th);
}

__device__ inline void gl_lds16(const short* g, short* l) {
    __builtin_amdgcn_global_load_lds(
        (const __attribute__((address_space(1))) void*)g,
        (__attribute__((address_space(3))) void*)l, 16, 0, 0);
}

// ---------------- weight transpose-convert ----------------
__global__ __launch_bounds__(256) void wtr_k(const float* __restrict__ in,
                                             short* __restrict__ out, int K, int N,
                                             int qrows, float qs)
{
    __shared__ float t[32][33];
    const int n0 = blockIdx.x * 32, k0 = blockIdx.y * 32;
    in  += (size_t)blockIdx.z * K * N;
    out += (size_t)blockIdx.z * K * N;
    const int tx = threadIdx.x & 31, ty = threadIdx.x >> 5;
    #pragma unroll
    for (int i = 0; i < 4; ++i)
        t[ty + 8 * i][tx] = in[(size_t)(k0 + ty + 8 * i) * N + n0 + tx];
    __syncthreads();
    #pragma unroll
    for (int i = 0; i < 4; ++i) {
        const int row = n0 + ty + 8 * i;
        float f = t[tx][ty + 8 * i];
        if (row < qrows) f *= qs;
        out[(size_t)row * K + k0 + tx] = f2bf(f);
    }
}

// ---------------- Y transpose-convert ----------------
__global__ __launch_bounds__(256) void ytr_k(const float* __restrict__ Y,
                                             short* __restrict__ out)
{
    __shared__ float t[32][33];
    const int b = blockIdx.z;
    const int t0 = blockIdx.x * 32, n0 = blockIdx.y * 32;
    const int tx = threadIdx.x & 31, ty = threadIdx.x >> 5;
    #pragma unroll
    for (int i = 0; i < 4; ++i) {
        const int tt = t0 + tx;
        t[ty + 8 * i][tx] = (tt < TT_)
            ? Y[((size_t)(b * NN_ + n0 + ty + 8 * i)) * TTOT_ + NPAD_ + tt] : 0.f;
    }
    __syncthreads();
    #pragma unroll
    for (int i = 0; i < 4; ++i) {
        const int tt = t0 + ty + 8 * i;
        if (tt < TT_)
            out[((size_t)(b * TT_ + tt)) * NN_ + n0 + tx] = f2bf(t[tx][ty + 8 * i]);
    }
}

// ---------------- positional-encoding table ----------------
__global__ void pe_k(float* __restrict__ PE)
{
    const int t = blockIdx.x, d = threadIdx.x;
    const float div = __expf(-(float)(d & ~1) * 0.0269834190585241f);
    const float ang = (float)t * div;
    PE[t * 256 + d] = (d & 1) ? cosf(ang) : sinf(ang);
}

// ---------------- scaled bias copy ----------------
__global__ void bscale_k(const float* __restrict__ in, float* __restrict__ out)
{
    const int i = blockIdx.x * 256 + threadIdx.x;
    if (i < 3072) {
        const int col = i % 768;
        out[i] = in[i] * ((col < 256) ? SC2_ : 1.f);
    }
}

// ---------------- bf16 MFMA GEMM (64x128, single-buffer) — embed only ----------------
// RES==2: + PE[(row%1000)][col]. Output bf16 only (residual stream).
__global__ __launch_bounds__(256) void bgemm_emb_k(const short* __restrict__ A,
                                                   const short* __restrict__ Bt,
                                                   const float* __restrict__ bias,
                                                   const float* __restrict__ PE,
                                                   short* __restrict__ Xb,
                                                   int M, int N, int K, int nby)
{
    __shared__ short As[64 * 64];
    __shared__ short Bs[128 * 64];
    const int tid = threadIdx.x;

    const int nwg = gridDim.x;
    int gid = blockIdx.x;
    {
        const int q = nwg >> 3, r = nwg & 7;
        const int x = gid & 7, idx = gid >> 3;
        gid = (x < r ? x * (q + 1) : r * (q + 1) + (x - r) * q) + idx;
    }
    const int bx = gid / nby, by = gid - bx * nby;
    const int m0 = bx * 64, n0 = by * 128;

    const int wv = tid >> 6, lane = tid & 63;
    const int wr = wv >> 1, wc = wv & 1;
    const int l15 = lane & 15, lg = lane >> 4;

    f32x4 acc[2][4];
    #pragma unroll
    for (int i = 0; i < 2; ++i)
        #pragma unroll
        for (int j = 0; j < 4; ++j) acc[i][j] = (f32x4){0.f, 0.f, 0.f, 0.f};

    const int nt = K >> 6;
    for (int t = 0; t < nt; ++t) {
        __syncthreads();
        const int k0 = t << 6;
        #pragma unroll
        for (int i = 0; i < 2; ++i) {
            const int cid = i * 256 + tid;
            const int r = cid >> 3, c = cid & 7;
            gl_lds16(A + (size_t)(m0 + r) * K + k0 + ((c ^ (r & 7)) * 8), As + cid * 8);
        }
        #pragma unroll
        for (int i = 0; i < 4; ++i) {
            const int cid = i * 256 + tid;
            const int r = cid >> 3, c = cid & 7;
            gl_lds16(Bt + (size_t)(n0 + r) * K + k0 + ((c ^ (r & 7)) * 8), Bs + cid * 8);
        }
        __syncthreads();

        #pragma unroll
        for (int ks = 0; ks < 2; ++ks) {
            s16x8 af[2], bf[4];
            #pragma unroll
            for (int mi = 0; mi < 2; ++mi) {
                const int row = wr * 32 + mi * 16 + l15;
                const int ch = ks * 4 + lg;
                af[mi] = *(const s16x8*)(As + row * 64 + ((ch ^ (row & 7)) * 8));
            }
            #pragma unroll
            for (int ni = 0; ni < 4; ++ni) {
                const int col = wc * 64 + ni * 16 + l15;
                const int ch = ks * 4 + lg;
                bf[ni] = *(const s16x8*)(Bs + col * 64 + ((ch ^ (col & 7)) * 8));
            }
            #pragma unroll
            for (int mi = 0; mi < 2; ++mi)
                #pragma unroll
                for (int ni = 0; ni < 4; ++ni)
                    acc[mi][ni] = __builtin_amdgcn_mfma_f32_16x16x32_bf16(
                        af[mi], bf[ni], acc[mi][ni], 0, 0, 0);
        }
    }

    #pragma unroll
    for (int mi = 0; mi < 2; ++mi) {
        #pragma unroll
        for (int ni = 0; ni < 4; ++ni) {
            const int col = n0 + wc * 64 + ni * 16 + l15;
            const float bv = bias[col];
            #pragma unroll
            for (int r = 0; r < 4; ++r) {
                const int row = m0 + wr * 32 + mi * 16 + lg * 4 + r;
                float v = acc[mi][ni][r] + bv + PE[(size_t)(row % 1000) * N + col];
                Xb[(size_t)row * N + col] = f2bf(v);
            }
        }
    }
}

// ---------------- bf16 MFMA GEMM (64x128, dbuf, counted vmcnt) — qkv / FF1 ----------------
template<int ACT, int COAL>
__global__ __launch_bounds__(256) void bgemm_db_k(const short* __restrict__ A,
                                                  const short* __restrict__ Bt,
                                                  const float* __restrict__ bias,
                                                  short* __restrict__ Cout,
                                                  int M, int N, int K, int nby)
{
    __shared__ short SH[2 * 12288];
    const int tid = threadIdx.x;

    const int nwg = gridDim.x;
    int gid = blockIdx.x;
    {
        const int q = nwg >> 3, r = nwg & 7;
        const int x = gid & 7, idx = gid >> 3;
        gid = (x < r ? x * (q + 1) : r * (q + 1) + (x - r) * q) + idx;
    }
    const int bx = gid / nby, by = gid - bx * nby;
    const int m0 = bx * 64, n0 = by * 128;

    const int wv = tid >> 6, lane = tid & 63;
    const int wr = wv >> 1, wc = wv & 1;
    const int l15 = lane & 15, lg = lane >> 4;

    f32x4 acc[2][4];
    #pragma unroll
    for (int i = 0; i < 2; ++i)
        #pragma unroll
        for (int j = 0; j < 4; ++j) acc[i][j] = (f32x4){0.f, 0.f, 0.f, 0.f};

    auto STAGE = [&](int p, int k0) {
        short* dA = SH + p * 12288;
        short* dB = dA + 4096;
        #pragma unroll
        for (int i = 0; i < 2; ++i) {
            const int cid = i * 256 + tid;
            const int r = cid >> 3, c = cid & 7;
            gl_lds16(A + (size_t)(m0 + r) * K + k0 + ((c ^ (r & 7)) * 8), dA + cid * 8);
        }
        #pragma unroll
        for (int i = 0; i < 4; ++i) {
            const int cid = i * 256 + tid;
            const int r = cid >> 3, c = cid & 7;
            gl_lds16(Bt + (size_t)(n0 + r) * K + k0 + ((c ^ (r & 7)) * 8), dB + cid * 8);
        }
    };

    const int nt = K >> 6;
    STAGE(0, 0);
    int cur = 0;
    for (int t = 0; t < nt; ++t) {
        if (t + 1 < nt) {
            STAGE(cur ^ 1, (t + 1) << 6);
            asm volatile("s_waitcnt vmcnt(6)" ::: "memory");
        } else {
            asm volatile("s_waitcnt vmcnt(0)" ::: "memory");
        }
        __builtin_amdgcn_s_barrier();

        const short* Asb = SH + cur * 12288;
        const short* Bsb = Asb + 4096;
        #pragma unroll
        for (int ks = 0; ks < 2; ++ks) {
            s16x8 af[2], bf[4];
            #pragma unroll
            for (int mi = 0; mi < 2; ++mi) {
                const int row = wr * 32 + mi * 16 + l15;
                const int ch = ks * 4 + lg;
                af[mi] = *(const s16x8*)(Asb + row * 64 + ((ch ^ (row & 7)) * 8));
            }
            #pragma unroll
            for (int ni = 0; ni < 4; ++ni) {
                const int col = wc * 64 + ni * 16 + l15;
                const int ch = ks * 4 + lg;
                bf[ni] = *(const s16x8*)(Bsb + col * 64 + ((ch ^ (col & 7)) * 8));
            }
            #pragma unroll
            for (int mi = 0; mi < 2; ++mi)
                #pragma unroll
                for (int ni = 0; ni < 4; ++ni)
                    acc[mi][ni] = __builtin_amdgcn_mfma_f32_16x16x32_bf16(
                        af[mi], bf[ni], acc[mi][ni], 0, 0, 0);
        }
        asm volatile("s_waitcnt lgkmcnt(0)" ::: "memory");
        __builtin_amdgcn_s_barrier();
        cur ^= 1;
    }

    if (COAL) {
        short* Cs = SH;
        #pragma unroll
        for (int mi = 0; mi < 2; ++mi)
            #pragma unroll
            for (int ni = 0; ni < 4; ++ni) {
                const int cl = wc * 64 + ni * 16 + l15;
                const float bv = bias[n0 + cl];
                #pragma unroll
                for (int r = 0; r < 4; ++r) {
                    const int rl = wr * 32 + mi * 16 + lg * 4 + r;
                    float v = acc[mi][ni][r] + bv;
                    if (ACT) v = gelu_f(v);
                    Cs[rl * 132 + cl] = f2bf(v);
                }
            }
        __syncthreads();
        #pragma unroll
        for (int i = 0; i < 4; ++i) {
            const int cid = i * 256 + tid;
            const int rl = cid >> 4, cc = (cid & 15) * 8;
            s16x8 vv = *(const s16x8*)(Cs + rl * 132 + cc);
            *(s16x8*)(Cout + (size_t)(m0 + rl) * N + n0 + cc) = vv;
        }
    } else {
        #pragma unroll
        for (int mi = 0; mi < 2; ++mi)
            #pragma unroll
            for (int ni = 0; ni < 4; ++ni) {
                const int col = n0 + wc * 64 + ni * 16 + l15;
                const float bv = bias[col];
                #pragma unroll
                for (int r = 0; r < 4; ++r) {
                    const int row = m0 + wr * 32 + mi * 16 + lg * 4 + r;
                    float v = acc[mi][ni][r] + bv;
                    if (ACT) v = gelu_f(v);
                    Cout[(size_t)row * N + col] = f2bf(v);
                }
            }
    }
}

// ---------------- fused GEMM(32x256 full-row) + resid(bf16) + LayerNorm ----------------
// Residual stream is bf16 Xb, read+written in place.
__global__ __launch_bounds__(512) void bgemmln_k(const short* __restrict__ A,
                                                 const short* __restrict__ Bt,
                                                 const float* __restrict__ bias,
                                                 const float* __restrict__ lng,
                                                 const float* __restrict__ lnb,
                                                 short* __restrict__ Xb,
                                                 int K)
{
    __shared__ short As[32 * 64];
    __shared__ short Bs[256 * 64];
    __shared__ float red[32][4][2];
    __shared__ float mrs[32][2];
    const int tid = threadIdx.x;

    const int nwg = gridDim.x;
    int gid = blockIdx.x;
    {
        const int q = nwg >> 3, r = nwg & 7;
        const int x = gid & 7, idx = gid >> 3;
        gid = (x < r ? x * (q + 1) : r * (q + 1) + (x - r) * q) + idx;
    }
    const int m0 = gid * 32;

    const int wv = tid >> 6, lane = tid & 63;
    const int wr = wv >> 2, wcx = wv & 3;
    const int l15 = lane & 15, lg = lane >> 4;

    f32x4 acc[4];
    #pragma unroll
    for (int j = 0; j < 4; ++j) acc[j] = (f32x4){0.f, 0.f, 0.f, 0.f};

    const int nt = K >> 6;
    for (int t = 0; t < nt; ++t) {
        __syncthreads();
        const int k0 = t << 6;
        if (tid < 256) {
            const int r = tid >> 3, c = tid & 7;
            gl_lds16(A + (size_t)(m0 + r) * K + k0 + ((c ^ (r & 7)) * 8), As + tid * 8);
        }
        #pragma unroll
        for (int i = 0; i < 4; ++i) {
            const int cid = i * 512 + tid;
            const int r = cid >> 3, c = cid & 7;
            gl_lds16(Bt + (size_t)r * K + k0 + ((c ^ (r & 7)) * 8), Bs + cid * 8);
        }
        __syncthreads();

        #pragma unroll
        for (int ks = 0; ks < 2; ++ks) {
            s16x8 af, bf[4];
            {
                const int row = wr * 16 + l15;
                const int ch = ks * 4 + lg;
                af = *(const s16x8*)(As + row * 64 + ((ch ^ (row & 7)) * 8));
            }
            #pragma unroll
            for (int ni = 0; ni < 4; ++ni) {
                const int col = wcx * 64 + ni * 16 + l15;
                const int ch = ks * 4 + lg;
                bf[ni] = *(const s16x8*)(Bs + col * 64 + ((ch ^ (col & 7)) * 8));
            }
            #pragma unroll
            for (int ni = 0; ni < 4; ++ni)
                acc[ni] = __builtin_amdgcn_mfma_f32_16x16x32_bf16(af, bf[ni], acc[ni], 0, 0, 0);
        }
    }

    float v[4][4];
    #pragma unroll
    for (int ni = 0; ni < 4; ++ni) {
        const int col = wcx * 64 + ni * 16 + l15;
        const float bv = bias[col];
        #pragma unroll
        for (int r = 0; r < 4; ++r) {
            const int row = m0 + wr * 16 + lg * 4 + r;
            v[ni][r] = acc[ni][r] + bv + bf2f(Xb[(size_t)row * 256 + col]);
        }
    }

    #pragma unroll
    for (int r = 0; r < 4; ++r) {
        float ss = v[0][r] + v[1][r] + v[2][r] + v[3][r];
        float qq = v[0][r] * v[0][r] + v[1][r] * v[1][r]
                 + v[2][r] * v[2][r] + v[3][r] * v[3][r];
        #pragma unroll
        for (int msk = 1; msk < 16; msk <<= 1) {
            ss += __shfl_xor(ss, msk);
            qq += __shfl_xor(qq, msk);
        }
        if (l15 == 0) {
            const int rloc = wr * 16 + lg * 4 + r;
            red[rloc][wcx][0] = ss;
            red[rloc][wcx][1] = qq;
        }
    }
    __syncthreads();
    if (tid < 32) {
        const float s = red[tid][0][0] + red[tid][1][0] + red[tid][2][0] + red[tid][3][0];
        const float q = red[tid][0][1] + red[tid][1][1] + red[tid][2][1] + red[tid][3][1];
        const float mean = s * (1.f / 256.f);
        const float var = q * (1.f / 256.f) - mean * mean;
        mrs[tid][0] = mean;
        mrs[tid][1] = rsqrtf(var + 1e-5f);
    }
    __syncthreads();

    #pragma unroll
    for (int ni = 0; ni < 4; ++ni) {
        const int col = wcx * 64 + ni * 16 + l15;
        const float gg = lng[col], bb = lnb[col];
        #pragma unroll
        for (int r = 0; r < 4; ++r) {
            const int rloc = wr * 16 + lg * 4 + r;
            const int row = m0 + rloc;
            const float o = (v[ni][r] - mrs[rloc][0]) * mrs[rloc][1] * gg + bb;
            Xb[(size_t)row * 256 + col] = f2bf(o);
        }
    }
}

// ---------------- MFMA flash attention ----------------
__global__ __launch_bounds__(512) void mattn_k(const short* __restrict__ qkv,
                                               short* __restrict__ o)
{
    int wg = blockIdx.x;
    wg = (wg & 7) * 64 + (wg >> 3);
    const int qt = wg & 3, h = (wg >> 2) & 7, b = wg >> 5;

    const int tid = threadIdx.x, wv = tid >> 6, lane = tid & 63;
    const int q31 = lane & 31, hi = lane >> 5;
    __shared__ short Ks[2][64 * 40];
    __shared__ short VT[2][32 * 72];

    const int q0w = qt * 256 + wv * 32;
    int qrow = q0w + q31; if (qrow > 999) qrow = 999;
    s16x8 bq[2];
    #pragma unroll
    for (int dh = 0; dh < 2; ++dh)
        bq[dh] = *(const s16x8*)(qkv + ((size_t)(b * TT_ + qrow)) * 768 + h * 32 + dh * 16 + hi * 8);

    f32x16 oacc;
    #pragma unroll
    for (int i = 0; i < 16; ++i) oacc[i] = 0.f;
    float lrun = 0.f;

    const int sr = tid >> 2, sc = tid & 3;
    const int u = tid & 255;
    const int kp = u >> 3, dq = (u & 7) * 4;
    s16x8 kreg;
    short4 va, vb;
    auto LOADT = [&](int kt) {
        if (tid < 256) {
            int t = kt * 64 + sr; if (t > 999) t = 999;
            kreg = *(const s16x8*)(qkv + ((size_t)(b * TT_ + t)) * 768 + 256 + h * 32 + sc * 8);
        } else {
            int t0 = kt * 64 + 2 * kp, t1 = t0 + 1;
            if (t0 > 999) t0 = 999;
            if (t1 > 999) t1 = 999;
            va = *(const short4*)(qkv + ((size_t)(b * TT_ + t0)) * 768 + 512 + h * 32 + dq);
            vb = *(const short4*)(qkv + ((size_t)(b * TT_ + t1)) * 768 + 512 + h * 32 + dq);
        }
    };
    auto WRITET = [&](int buf) {
        if (tid < 256) {
            *(s16x8*)(&Ks[buf][sr * 40 + sc * 8]) = kreg;
        } else {
            const int c = kp >> 2;
            const int ko = (2 * kp) & 7;
            const uint2 vaw = *(const uint2*)&va;
            const uint2 vbw = *(const uint2*)&vb;
            unsigned pk[4];
            pk[0] = __builtin_amdgcn_perm(vbw.x, vaw.x, 0x05040100u);
            pk[1] = __builtin_amdgcn_perm(vbw.x, vaw.x, 0x07060302u);
            pk[2] = __builtin_amdgcn_perm(vbw.y, vaw.y, 0x05040100u);
            pk[3] = __builtin_amdgcn_perm(vbw.y, vaw.y, 0x07060302u);
            #pragma unroll
            for (int j = 0; j < 4; ++j) {
                const int d = dq + j;
                *(unsigned*)(&VT[buf][d * 72 + ((c ^ (d >> 3)) * 8) + ko]) = pk[j];
            }
        }
    };

    LOADT(0); WRITET(0);
    __syncthreads();
    int cur = 0;

    for (int kt = 0; kt < 16; ++kt) {
        if (kt < 15) LOADT(kt + 1);

        f32x16 st[2];
        __builtin_amdgcn_s_setprio(1);
        #pragma unroll
        for (int kb = 0; kb < 2; ++kb) {
            s16x8 kf0 = *(const s16x8*)(&Ks[cur][(kb * 32 + q31) * 40 + hi * 8]);
            s16x8 kf1 = *(const s16x8*)(&Ks[cur][(kb * 32 + q31) * 40 + 16 + hi * 8]);
            f32x16 z;
            #pragma unroll
            for (int i = 0; i < 16; ++i) z[i] = 0.f;
            z = __builtin_amdgcn_mfma_f32_32x32x16_bf16(kf0, bq[0], z, 0, 0, 0);
            z = __builtin_amdgcn_mfma_f32_32x32x16_bf16(kf1, bq[1], z, 0, 0, 0);
            st[kb] = z;
        }
        __builtin_amdgcn_s_setprio(0);

        if (kt == 15) {
            #pragma unroll
            for (int kb = 0; kb < 2; ++kb)
                #pragma unroll
                for (int r = 0; r < 16; ++r) {
                    const int kloc = kb * 32 + (r & 3) + 8 * (r >> 2) + 4 * hi;
                    if (960 + kloc >= TT_) st[kb][r] = -1e30f;
                }
        }

        float sloc = 0.f;
        #pragma unroll
        for (int kb = 0; kb < 2; ++kb)
            #pragma unroll
            for (int r = 0; r < 16; ++r) {
                const float p = exp2i(st[kb][r]);
                st[kb][r] = p; sloc += p;
            }
        lrun += sloc;

        unsigned wk[2][4][2];
        #pragma unroll
        for (int kb = 0; kb < 2; ++kb)
            #pragma unroll
            for (int a = 0; a < 4; ++a)
                #pragma unroll
                for (int h2 = 0; h2 < 2; ++h2) {
                    unsigned rr;
                    asm("v_cvt_pk_bf16_f32 %0, %1, %2"
                        : "=v"(rr)
                        : "v"(st[kb][4 * a + 2 * h2]), "v"(st[kb][4 * a + 2 * h2 + 1]));
                    wk[kb][a][h2] = rr;
                }

        #pragma unroll
        for (int ks = 0; ks < 4; ++ks) {
            const int kb = ks >> 1, qq = ks & 1;
            unsigned X0 = wk[kb][2 * qq + 1][0], Y0 = wk[kb][2 * qq][0];
            unsigned X1 = wk[kb][2 * qq + 1][1], Y1 = wk[kb][2 * qq][1];
            asm("v_permlane32_swap_b32 %0, %1" : "+v"(X0), "+v"(Y0));
            asm("v_permlane32_swap_b32 %0, %1" : "+v"(X1), "+v"(Y1));
            u32x4 w4 = (u32x4){Y0, Y1, X0, X1};
            s16x8 pb = __builtin_bit_cast(s16x8, w4);
            s16x8 vf = *(const s16x8*)(&VT[cur][q31 * 72 + (((2 * ks + hi) ^ (q31 >> 3)) * 8)]);
            __builtin_amdgcn_s_setprio(1);
            oacc = __builtin_amdgcn_mfma_f32_32x32x16_bf16(vf, pb, oacc, 0, 0, 0);
            __builtin_amdgcn_s_setprio(0);
        }

        if (kt < 15) WRITET(cur ^ 1);
        __syncthreads();
        cur ^= 1;
    }

    lrun += __shfl_xor(lrun, 32);

    const int t = q0w + q31;
    if (t < TT_) {
        const float inv = 1.f / lrun;
        short* ob = o + ((size_t)(b * TT_ + t)) * 256 + h * 32;
        #pragma unroll
        for (int a = 0; a < 4; ++a) {
            unsigned w0, w1;
            asm("v_cvt_pk_bf16_f32 %0, %1, %2"
                : "=v"(w0) : "v"(oacc[4 * a + 0] * inv), "v"(oacc[4 * a + 1] * inv));
            asm("v_cvt_pk_bf16_f32 %0, %1, %2"
                : "=v"(w1) : "v"(oacc[4 * a + 2] * inv), "v"(oacc[4 * a + 3] * inv));
            const int d0 = 8 * a + 4 * hi;
            *(unsigned*)(ob + d0) = w0;
            *(unsigned*)(ob + d0 + 2) = w1;
        }
    }
}

// ---------------- mean pool (bf16 input) ----------------
__global__ __launch_bounds__(256) void pool_part_k(const short* __restrict__ Xb,
                                                   float* __restrict__ partial)
{
    const int b = blockIdx.x, seg = blockIdx.y, d = threadIdx.x;
    float s = 0.f;
    const int t0 = seg * 125;
    for (int t = t0; t < t0 + 125; ++t) s += bf2f(Xb[((size_t)b * TT_ + t) * 256 + d]);
    partial[(b * 8 + seg) * 256 + d] = s;
}
__global__ __launch_bounds__(256) void pool_red_k(const float* __restrict__ partial,
                                                  float* __restrict__ pooled)
{
    const int b = blockIdx.x, d = threadIdx.x;
    float s = 0.f;
    for (int k = 0; k < 8; ++k) s += partial[(b * 8 + k) * 256 + d];
    pooled[b * 256 + d] = s * (1.f / (float)TT_);
}

// ---------------- decode head ----------------
__global__ __launch_bounds__(128) void head_k(const float* __restrict__ pooled,
                                              const float* __restrict__ toLW,
                                              const float* __restrict__ toLb,
                                              const float* __restrict__ dW1,
                                              const float* __restrict__ db1,
                                              const float* __restrict__ dW2,
                                              const float* __restrict__ db2,
                                              float* __restrict__ coeffs)
{
    const int b = blockIdx.x, j = threadIdx.x;
    __shared__ float hs[64];
    __shared__ float hid[128];
    float a = toLb[j];
    for (int d = 0; d < 256; ++d) a += pooled[b * 256 + d] * toLW[d * 128 + j];
    if (j < 64) hs[j] = a;
    __syncthreads();
    float a2 = db1[j];
    for (int z = 0; z < 64; ++z) a2 += hs[z] * dW1[z * 128 + j];
    hid[j] = fmaxf(a2, 0.f);
    __syncthreads();
    if (j < 120) {
        float a3 = db2[j];
        for (int k = 0; k < 128; ++k) a3 += hid[k] * dW2[k * 120 + j];
        coeffs[b * 120 + j] = a3;
    }
}

// ---------------- combined conv kernel ----------------
__global__ void comb_k(const float* __restrict__ selfK,
                       const float* __restrict__ cplW,
                       const float* __restrict__ cplB,
                       float* __restrict__ comb)
{
    const int n = threadIdx.x;
    for (int ti = 0; ti < 20; ++ti) {
        float s = selfK[ti * 256 + n];
        #pragma unroll
        for (int si = 0; si < 4; ++si) s += cplW[n * 4 + si] * cplB[ti * 4 + si];
        comb[n * 20 + ti] = s;
    }
}

// ---------------- sti_lat ----------------
__global__ __launch_bounds__(256) void stilat_k(const float* __restrict__ SB,
                                                const float* __restrict__ coeffs,
                                                float* __restrict__ STL)
{
    const int bf = blockIdx.x;
    __shared__ float c[30];
    if (threadIdx.x < 30) c[threadIdx.x] = coeffs[(bf >> 2) * 120 + (bf & 3) * 30 + threadIdx.x];
    __syncthreads();
    for (int t = threadIdx.x; t < TT_; t += 256) {
        float acc = 0.f;
        const float* sp = SB + (size_t)t * 30;
        #pragma unroll
        for (int k = 0; k < 30; ++k) acc += c[k] * sp[k];
        STL[bf * TT_ + t] = acc;
    }
}

// ---------------- final ----------------
__global__ __launch_bounds__(256) void final_k(const float* __restrict__ Y,
                                               const float* __restrict__ STL,
                                               const float* __restrict__ roW,
                                               const float* __restrict__ comb,
                                               float* __restrict__ out)
{
    const int bx = blockIdx.x;
    const int ts = bx & 3, nc = (bx >> 2) & 31, b = bx >> 7;
    const int n0 = nc * 8, t0 = ts * 250;
    const int tid = threadIdx.x;
    __shared__ float rw[8][4], ck[8][20], yl[8][272];

    if (tid < 32) rw[tid >> 2][tid & 3] = roW[(n0 + (tid >> 2)) * 4 + (tid & 3)];
    if (tid >= 64 && tid < 224) {
        const int j = tid - 64;
        ck[j / 20][j % 20] = comb[(n0 + j / 20) * 20 + (j % 20)];
    }
    for (int j = tid; j < 2160; j += 256) {
        const int n = j / 270, jj = j - n * 270;
        yl[n][jj] = Y[((size_t)(b * 256 + n0 + n)) * TTOT_ + t0 + 80 + jj];
    }
    __syncthreads();

    if (tid < 250) {
        const int t = t0 + tid;
        float s4[4];
        #pragma unroll
        for (int f = 0; f < 4; ++f) s4[f] = STL[((size_t)b * 4 + f) * TT_ + t];
        #pragma unroll
        for (int n = 0; n < 8; ++n) {
            float acc = rw[n][0] * s4[0] + rw[n][1] * s4[1]
                      + rw[n][2] * s4[2] + rw[n][3] * s4[3];
            #pragma unroll
            for (int tau = 1; tau <= 20; ++tau)
                acc += ck[n][tau - 1] * yl[n][tid + 20 - tau];
            out[((size_t)(b * 256 + n0 + n)) * TT_ + t] = acc;
        }
    }
}

// ---------------- launch ----------------
extern "C" void kernel_launch(void* const* d_in, const int* in_sizes, int n_in,
                              void* d_out, int out_size, void* d_ws, size_t ws_size,
                              hipStream_t stream)
{
    const float* Y      = (const float*)d_in[0];
    const float* tokW   = (const float*)d_in[1];
    const float* tokb   = (const float*)d_in[2];
    const float* Wqkv   = (const float*)d_in[3];
    const float* bqkv   = (const float*)d_in[4];
    const float* Wo     = (const float*)d_in[5];
    const float* bo     = (const float*)d_in[6];
    const float* ln1g   = (const float*)d_in[7];
    const float* ln1b   = (const float*)d_in[8];
    const float* W1     = (const float*)d_in[9];
    const float* b1     = (const float*)d_in[10];
    const float* W2     = (const float*)d_in[11];
    const float* b2     = (const float*)d_in[12];
    const float* ln2g   = (const float*)d_in[13];
    const float* ln2b   = (const float*)d_in[14];
    const float* toLW   = (const float*)d_in[15];
    const float* toLb   = (const float*)d_in[16];
    const float* dW1    = (const float*)d_in[17];
    const float* db1    = (const float*)d_in[18];
    const float* dW2    = (const float*)d_in[19];
    const float* db2    = (const float*)d_in[20];
    const float* SB     = (const float*)d_in[21];
    const float* roW    = (const float*)d_in[22];
    const float* cplW   = (const float*)d_in[23];
    const float* cplB   = (const float*)d_in[24];
    const float* selfK  = (const float*)d_in[25];

    float* ws  = (float*)d_ws;
    short* Xb  = (short*)(ws + XB_OFF);
    short* O   = (short*)(ws + O_OFF);
    short* BIG = (short*)(ws + BIG_OFF);
    short* WT  = (short*)(ws + WT_OFF);
    float* PE  = ws + PE_OFF;
    float* PP  = ws + PP_OFF;
    float* PL  = ws + PL_OFF;
    float* CF  = ws + CF_OFF;
    float* CB  = ws + CB_OFF;
    float* BQ  = ws + BQ_OFF;
    float* STL = ws + STL_OFF;

    short* WTqkv = WT;
    short* WTo   = WT + 786432;
    short* WTw1  = WT + 1048576;
    short* WTw2  = WT + 2097152;
    short* WTtok = WT + 3145728;
    short* Ybt   = BIG;

    wtr_k<<<dim3(24, 8, 4), 256, 0, stream>>>(Wqkv, WTqkv, 256, 768, 256, SC2_);
    wtr_k<<<dim3(8, 8, 4),  256, 0, stream>>>(Wo,   WTo,   256, 256, 0, 1.f);
    wtr_k<<<dim3(32, 8, 4), 256, 0, stream>>>(W1,   WTw1,  256, 1024, 0, 1.f);
    wtr_k<<<dim3(8, 32, 4), 256, 0, stream>>>(W2,   WTw2,  1024, 256, 0, 1.f);
    wtr_k<<<dim3(8, 8, 1),  256, 0, stream>>>(tokW, WTtok, 256, 256, 0, 1.f);
    bscale_k<<<12, 256, 0, stream>>>(bqkv, BQ);
    pe_k<<<1000, 256, 0, stream>>>(PE);
    ytr_k<<<dim3(32, 8, 16), 256, 0, stream>>>(Y, Ybt);

    bgemm_emb_k<<<500, 256, 0, stream>>>(
        Ybt, WTtok, tokb, PE, Xb, 16000, 256, 256, 2);

    for (int l = 0; l < 4; ++l) {
        bgemm_db_k<0, 0><<<1500, 256, 0, stream>>>(
            Xb, WTqkv + (size_t)l * 196608, BQ + l * 768, BIG,
            16000, 768, 256, 6);
        mattn_k<<<512, 512, 0, stream>>>(BIG, O);
        bgemmln_k<<<500, 512, 0, stream>>>(
            O, WTo + (size_t)l * 65536, bo + l * 256,
            ln1g + l * 256, ln1b + l * 256, Xb, 256);
        bgemm_db_k<1, 1><<<2000, 256, 0, stream>>>(
            Xb, WTw1 + (size_t)l * 262144, b1 + l * 1024, BIG,
            16000, 1024, 256, 8);
        bgemmln_k<<<500, 512, 0, stream>>>(
            BIG, WTw2 + (size_t)l * 262144, b2 + l * 256,
            ln2g + l * 256, ln2b + l * 256, Xb, 1024);
    }

    pool_part_k<<<dim3(16, 8), 256, 0, stream>>>(Xb, PP);
    pool_red_k<<<16, 256, 0, stream>>>(PP, PL);
    head_k<<<16, 128, 0, stream>>>(PL, toLW, toLb, dW1, db1, dW2, db2, CF);
    comb_k<<<1, 256, 0, stream>>>(selfK, cplW, cplB, CB);
    stilat_k<<<64, 256, 0, stream>>>(SB, CF, STL);
    final_k<<<2048, 256, 0, stream>>>(Y, STL, roW, CB, (float*)d_out);
}

// Round 18
// 465.165 us; speedup vs baseline: 1.4574x; 1.0056x over previous
//
#include <hip/hip_runtime.h>
#include <math.h>

// ---------------- problem constants ----------------
#define TT_   1000
#define TTOT_ 1100
#define NPAD_ 100
#define DD_   256
#define NN_   256

// workspace layout (float units)
#define XB_OFF   4096000u      // bf16 residual stream 16000x256
#define O_OFF    6144000u
#define BIG_OFF  12288000u
#define WT_OFF   20480000u
#define PE_OFF   22085632u
#define PP_OFF   22341632u
#define PL_OFF   (PP_OFF + 32768u)
#define CF_OFF   (PL_OFF + 4096u)
#define CB_OFF   (CF_OFF + 1920u)
#define BQ_OFF   (CF_OFF + 1920u + 5120u)
#define STL_OFF  (BQ_OFF + 3072u)

#define SC2_ 0.25503902254649546f   // (1/sqrt(32)) * log2(e)

typedef __attribute__((ext_vector_type(8))) short s16x8;
typedef __attribute__((ext_vector_type(4))) float f32x4;
typedef __attribute__((ext_vector_type(16))) float f32x16;
typedef __attribute__((ext_vector_type(4))) unsigned u32x4;

__device__ inline short f2bf(float f) {
    unsigned u = __float_as_uint(f);
    u += 0x7fffu + ((u >> 16) & 1u);
    return (short)(u >> 16);
}
__device__ inline float bf2f(short s) {
    return __uint_as_float(((unsigned)(unsigned short)s) << 16);
}
__device__ inline float exp2i(float x) {
    float r; asm("v_exp_f32 %0, %1" : "=v"(r) : "v"(x)); return r;
}
__device__ inline float gelu_f(float v) {
    const float t = v * (0.7978845608f + 0.0356774081f * v * v);
    const float e = exp2i(t * 2.885390082f);
    const float th = 1.f - 2.f / (e + 1.f);
    return 0.5f * v * (1.f + th);
}

__device__ inline void gl_lds16(const short* g, short* l) {
    __builtin_amdgcn_global_load_lds(
        (const __attribute__((address_space(1))) void*)g,
        (__attribute__((address_space(3))) void*)l, 16, 0, 0);
}

// ---------------- weight transpose-convert ----------------
__global__ __launch_bounds__(256) void wtr_k(const float* __restrict__ in,
                                             short* __restrict__ out, int K, int N,
                                             int qrows, float qs)
{
    __shared__ float t[32][33];
    const int n0 = blockIdx.x * 32, k0 = blockIdx.y * 32;
    in  += (size_t)blockIdx.z * K * N;
    out += (size_t)blockIdx.z * K * N;
    const int tx = threadIdx.x & 31, ty = threadIdx.x >> 5;
    #pragma unroll
    for (int i = 0; i < 4; ++i)
        t[ty + 8 * i][tx] = in[(size_t)(k0 + ty + 8 * i) * N + n0 + tx];
    __syncthreads();
    #pragma unroll
    for (int i = 0; i < 4; ++i) {
        const int row = n0 + ty + 8 * i;
        float f = t[tx][ty + 8 * i];
        if (row < qrows) f *= qs;
        out[(size_t)row * K + k0 + tx] = f2bf(f);
    }
}

// ---------------- Y transpose-convert ----------------
__global__ __launch_bounds__(256) void ytr_k(const float* __restrict__ Y,
                                             short* __restrict__ out)
{
    __shared__ float t[32][33];
    const int b = blockIdx.z;
    const int t0 = blockIdx.x * 32, n0 = blockIdx.y * 32;
    const int tx = threadIdx.x & 31, ty = threadIdx.x >> 5;
    #pragma unroll
    for (int i = 0; i < 4; ++i) {
        const int tt = t0 + tx;
        t[ty + 8 * i][tx] = (tt < TT_)
            ? Y[((size_t)(b * NN_ + n0 + ty + 8 * i)) * TTOT_ + NPAD_ + tt] : 0.f;
    }
    __syncthreads();
    #pragma unroll
    for (int i = 0; i < 4; ++i) {
        const int tt = t0 + ty + 8 * i;
        if (tt < TT_)
            out[((size_t)(b * TT_ + tt)) * NN_ + n0 + tx] = f2bf(t[tx][ty + 8 * i]);
    }
}

// ---------------- positional-encoding table ----------------
__global__ void pe_k(float* __restrict__ PE)
{
    const int t = blockIdx.x, d = threadIdx.x;
    const float div = __expf(-(float)(d & ~1) * 0.0269834190585241f);
    const float ang = (float)t * div;
    PE[t * 256 + d] = (d & 1) ? cosf(ang) : sinf(ang);
}

// ---------------- scaled bias copy ----------------
__global__ void bscale_k(const float* __restrict__ in, float* __restrict__ out)
{
    const int i = blockIdx.x * 256 + threadIdx.x;
    if (i < 3072) {
        const int col = i % 768;
        out[i] = in[i] * ((col < 256) ? SC2_ : 1.f);
    }
}

// ---------------- embed GEMM (64x128, single-buffer), bf16 out + PE ----------------
__global__ __launch_bounds__(256) void bgemm_emb_k(const short* __restrict__ A,
                                                   const short* __restrict__ Bt,
                                                   const float* __restrict__ bias,
                                                   const float* __restrict__ PE,
                                                   short* __restrict__ Xb,
                                                   int M, int N, int K, int nby)
{
    __shared__ short As[64 * 64];
    __shared__ short Bs[128 * 64];
    const int tid = threadIdx.x;

    const int nwg = gridDim.x;
    int gid = blockIdx.x;
    {
        const int q = nwg >> 3, r = nwg & 7;
        const int x = gid & 7, idx = gid >> 3;
        gid = (x < r ? x * (q + 1) : r * (q + 1) + (x - r) * q) + idx;
    }
    const int bx = gid / nby, by = gid - bx * nby;
    const int m0 = bx * 64, n0 = by * 128;

    const int wv = tid >> 6, lane = tid & 63;
    const int wr = wv >> 1, wc = wv & 1;
    const int l15 = lane & 15, lg = lane >> 4;

    f32x4 acc[2][4];
    #pragma unroll
    for (int i = 0; i < 2; ++i)
        #pragma unroll
        for (int j = 0; j < 4; ++j) acc[i][j] = (f32x4){0.f, 0.f, 0.f, 0.f};

    const int nt = K >> 6;
    for (int t = 0; t < nt; ++t) {
        __syncthreads();
        const int k0 = t << 6;
        #pragma unroll
        for (int i = 0; i < 2; ++i) {
            const int cid = i * 256 + tid;
            const int r = cid >> 3, c = cid & 7;
            gl_lds16(A + (size_t)(m0 + r) * K + k0 + ((c ^ (r & 7)) * 8), As + cid * 8);
        }
        #pragma unroll
        for (int i = 0; i < 4; ++i) {
            const int cid = i * 256 + tid;
            const int r = cid >> 3, c = cid & 7;
            gl_lds16(Bt + (size_t)(n0 + r) * K + k0 + ((c ^ (r & 7)) * 8), Bs + cid * 8);
        }
        __syncthreads();

        #pragma unroll
        for (int ks = 0; ks < 2; ++ks) {
            s16x8 af[2], bf[4];
            #pragma unroll
            for (int mi = 0; mi < 2; ++mi) {
                const int row = wr * 32 + mi * 16 + l15;
                const int ch = ks * 4 + lg;
                af[mi] = *(const s16x8*)(As + row * 64 + ((ch ^ (row & 7)) * 8));
            }
            #pragma unroll
            for (int ni = 0; ni < 4; ++ni) {
                const int col = wc * 64 + ni * 16 + l15;
                const int ch = ks * 4 + lg;
                bf[ni] = *(const s16x8*)(Bs + col * 64 + ((ch ^ (col & 7)) * 8));
            }
            #pragma unroll
            for (int mi = 0; mi < 2; ++mi)
                #pragma unroll
                for (int ni = 0; ni < 4; ++ni)
                    acc[mi][ni] = __builtin_amdgcn_mfma_f32_16x16x32_bf16(
                        af[mi], bf[ni], acc[mi][ni], 0, 0, 0);
        }
    }

    #pragma unroll
    for (int mi = 0; mi < 2; ++mi) {
        #pragma unroll
        for (int ni = 0; ni < 4; ++ni) {
            const int col = n0 + wc * 64 + ni * 16 + l15;
            const float bv = bias[col];
            #pragma unroll
            for (int r = 0; r < 4; ++r) {
                const int row = m0 + wr * 32 + mi * 16 + lg * 4 + r;
                float v = acc[mi][ni][r] + bv + PE[(size_t)(row % 1000) * N + col];
                Xb[(size_t)row * N + col] = f2bf(v);
            }
        }
    }
}

// ---------------- bf16 MFMA GEMM (64x128, SINGLE-buffer, 24KB LDS) — qkv / FF1 ----------------
// COAL=0: direct stores (qkv). COAL=1: LDS-coalesced stores + gelu (FF1).
template<int ACT, int COAL>
__global__ __launch_bounds__(256) void bgemm_sb_k(const short* __restrict__ A,
                                                  const short* __restrict__ Bt,
                                                  const float* __restrict__ bias,
                                                  short* __restrict__ Cout,
                                                  int M, int N, int K, int nby)
{
    __shared__ short SH[12288];   // A 64x64 (4096) | B 128x64 (8192); epilogue reuse
    const int tid = threadIdx.x;

    const int nwg = gridDim.x;
    int gid = blockIdx.x;
    {
        const int q = nwg >> 3, r = nwg & 7;
        const int x = gid & 7, idx = gid >> 3;
        gid = (x < r ? x * (q + 1) : r * (q + 1) + (x - r) * q) + idx;
    }
    const int bx = gid / nby, by = gid - bx * nby;
    const int m0 = bx * 64, n0 = by * 128;

    const int wv = tid >> 6, lane = tid & 63;
    const int wr = wv >> 1, wc = wv & 1;
    const int l15 = lane & 15, lg = lane >> 4;

    short* As = SH;
    short* Bs = SH + 4096;

    f32x4 acc[2][4];
    #pragma unroll
    for (int i = 0; i < 2; ++i)
        #pragma unroll
        for (int j = 0; j < 4; ++j) acc[i][j] = (f32x4){0.f, 0.f, 0.f, 0.f};

    const int nt = K >> 6;
    for (int t = 0; t < nt; ++t) {
        __syncthreads();
        const int k0 = t << 6;
        #pragma unroll
        for (int i = 0; i < 2; ++i) {
            const int cid = i * 256 + tid;
            const int r = cid >> 3, c = cid & 7;
            gl_lds16(A + (size_t)(m0 + r) * K + k0 + ((c ^ (r & 7)) * 8), As + cid * 8);
        }
        #pragma unroll
        for (int i = 0; i < 4; ++i) {
            const int cid = i * 256 + tid;
            const int r = cid >> 3, c = cid & 7;
            gl_lds16(Bt + (size_t)(n0 + r) * K + k0 + ((c ^ (r & 7)) * 8), Bs + cid * 8);
        }
        __syncthreads();

        #pragma unroll
        for (int ks = 0; ks < 2; ++ks) {
            s16x8 af[2], bf[4];
            #pragma unroll
            for (int mi = 0; mi < 2; ++mi) {
                const int row = wr * 32 + mi * 16 + l15;
                const int ch = ks * 4 + lg;
                af[mi] = *(const s16x8*)(As + row * 64 + ((ch ^ (row & 7)) * 8));
            }
            #pragma unroll
            for (int ni = 0; ni < 4; ++ni) {
                const int col = wc * 64 + ni * 16 + l15;
                const int ch = ks * 4 + lg;
                bf[ni] = *(const s16x8*)(Bs + col * 64 + ((ch ^ (col & 7)) * 8));
            }
            #pragma unroll
            for (int mi = 0; mi < 2; ++mi)
                #pragma unroll
                for (int ni = 0; ni < 4; ++ni)
                    acc[mi][ni] = __builtin_amdgcn_mfma_f32_16x16x32_bf16(
                        af[mi], bf[ni], acc[mi][ni], 0, 0, 0);
        }
    }

    if (COAL) {
        __syncthreads();
        short* Cs = SH;   // 64*132 = 8448 shorts < 12288
        #pragma unroll
        for (int mi = 0; mi < 2; ++mi)
            #pragma unroll
            for (int ni = 0; ni < 4; ++ni) {
                const int cl = wc * 64 + ni * 16 + l15;
                const float bv = bias[n0 + cl];
                #pragma unroll
                for (int r = 0; r < 4; ++r) {
                    const int rl = wr * 32 + mi * 16 + lg * 4 + r;
                    float v = acc[mi][ni][r] + bv;
                    if (ACT) v = gelu_f(v);
                    Cs[rl * 132 + cl] = f2bf(v);
                }
            }
        __syncthreads();
        #pragma unroll
        for (int i = 0; i < 4; ++i) {
            const int cid = i * 256 + tid;
            const int rl = cid >> 4, cc = (cid & 15) * 8;
            s16x8 vv = *(const s16x8*)(Cs + rl * 132 + cc);
            *(s16x8*)(Cout + (size_t)(m0 + rl) * N + n0 + cc) = vv;
        }
    } else {
        #pragma unroll
        for (int mi = 0; mi < 2; ++mi)
            #pragma unroll
            for (int ni = 0; ni < 4; ++ni) {
                const int col = n0 + wc * 64 + ni * 16 + l15;
                const float bv = bias[col];
                #pragma unroll
                for (int r = 0; r < 4; ++r) {
                    const int row = m0 + wr * 32 + mi * 16 + lg * 4 + r;
                    float v = acc[mi][ni][r] + bv;
                    if (ACT) v = gelu_f(v);
                    Cout[(size_t)row * N + col] = f2bf(v);
                }
            }
    }
}

// ---------------- fused GEMM(32x256 full-row) + resid(bf16) + LayerNorm ----------------
__global__ __launch_bounds__(512) void bgemmln_k(const short* __restrict__ A,
                                                 const short* __restrict__ Bt,
                                                 const float* __restrict__ bias,
                                                 const float* __restrict__ lng,
                                                 const float* __restrict__ lnb,
                                                 short* __restrict__ Xb,
                                                 int K)
{
    __shared__ short As[32 * 64];
    __shared__ short Bs[256 * 64];
    __shared__ float red[32][4][2];
    __shared__ float mrs[32][2];
    const int tid = threadIdx.x;

    const int nwg = gridDim.x;
    int gid = blockIdx.x;
    {
        const int q = nwg >> 3, r = nwg & 7;
        const int x = gid & 7, idx = gid >> 3;
        gid = (x < r ? x * (q + 1) : r * (q + 1) + (x - r) * q) + idx;
    }
    const int m0 = gid * 32;

    const int wv = tid >> 6, lane = tid & 63;
    const int wr = wv >> 2, wcx = wv & 3;
    const int l15 = lane & 15, lg = lane >> 4;

    f32x4 acc[4];
    #pragma unroll
    for (int j = 0; j < 4; ++j) acc[j] = (f32x4){0.f, 0.f, 0.f, 0.f};

    const int nt = K >> 6;
    for (int t = 0; t < nt; ++t) {
        __syncthreads();
        const int k0 = t << 6;
        if (tid < 256) {
            const int r = tid >> 3, c = tid & 7;
            gl_lds16(A + (size_t)(m0 + r) * K + k0 + ((c ^ (r & 7)) * 8), As + tid * 8);
        }
        #pragma unroll
        for (int i = 0; i < 4; ++i) {
            const int cid = i * 512 + tid;
            const int r = cid >> 3, c = cid & 7;
            gl_lds16(Bt + (size_t)r * K + k0 + ((c ^ (r & 7)) * 8), Bs + cid * 8);
        }
        __syncthreads();

        #pragma unroll
        for (int ks = 0; ks < 2; ++ks) {
            s16x8 af, bf[4];
            {
                const int row = wr * 16 + l15;
                const int ch = ks * 4 + lg;
                af = *(const s16x8*)(As + row * 64 + ((ch ^ (row & 7)) * 8));
            }
            #pragma unroll
            for (int ni = 0; ni < 4; ++ni) {
                const int col = wcx * 64 + ni * 16 + l15;
                const int ch = ks * 4 + lg;
                bf[ni] = *(const s16x8*)(Bs + col * 64 + ((ch ^ (col & 7)) * 8));
            }
            #pragma unroll
            for (int ni = 0; ni < 4; ++ni)
                acc[ni] = __builtin_amdgcn_mfma_f32_16x16x32_bf16(af, bf[ni], acc[ni], 0, 0, 0);
        }
    }

    float v[4][4];
    #pragma unroll
    for (int ni = 0; ni < 4; ++ni) {
        const int col = wcx * 64 + ni * 16 + l15;
        const float bv = bias[col];
        #pragma unroll
        for (int r = 0; r < 4; ++r) {
            const int row = m0 + wr * 16 + lg * 4 + r;
            v[ni][r] = acc[ni][r] + bv + bf2f(Xb[(size_t)row * 256 + col]);
        }
    }

    #pragma unroll
    for (int r = 0; r < 4; ++r) {
        float ss = v[0][r] + v[1][r] + v[2][r] + v[3][r];
        float qq = v[0][r] * v[0][r] + v[1][r] * v[1][r]
                 + v[2][r] * v[2][r] + v[3][r] * v[3][r];
        #pragma unroll
        for (int msk = 1; msk < 16; msk <<= 1) {
            ss += __shfl_xor(ss, msk);
            qq += __shfl_xor(qq, msk);
        }
        if (l15 == 0) {
            const int rloc = wr * 16 + lg * 4 + r;
            red[rloc][wcx][0] = ss;
            red[rloc][wcx][1] = qq;
        }
    }
    __syncthreads();
    if (tid < 32) {
        const float s = red[tid][0][0] + red[tid][1][0] + red[tid][2][0] + red[tid][3][0];
        const float q = red[tid][0][1] + red[tid][1][1] + red[tid][2][1] + red[tid][3][1];
        const float mean = s * (1.f / 256.f);
        const float var = q * (1.f / 256.f) - mean * mean;
        mrs[tid][0] = mean;
        mrs[tid][1] = rsqrtf(var + 1e-5f);
    }
    __syncthreads();

    #pragma unroll
    for (int ni = 0; ni < 4; ++ni) {
        const int col = wcx * 64 + ni * 16 + l15;
        const float gg = lng[col], bb = lnb[col];
        #pragma unroll
        for (int r = 0; r < 4; ++r) {
            const int rloc = wr * 16 + lg * 4 + r;
            const int row = m0 + rloc;
            const float o = (v[ni][r] - mrs[rloc][0]) * mrs[rloc][1] * gg + bb;
            Xb[(size_t)row * 256 + col] = f2bf(o);
        }
    }
}

// ---------------- MFMA flash attention ----------------
__global__ __launch_bounds__(512) void mattn_k(const short* __restrict__ qkv,
                                               short* __restrict__ o)
{
    int wg = blockIdx.x;
    wg = (wg & 7) * 64 + (wg >> 3);
    const int qt = wg & 3, h = (wg >> 2) & 7, b = wg >> 5;

    const int tid = threadIdx.x, wv = tid >> 6, lane = tid & 63;
    const int q31 = lane & 31, hi = lane >> 5;
    __shared__ short Ks[2][64 * 40];
    __shared__ short VT[2][32 * 72];

    const int q0w = qt * 256 + wv * 32;
    int qrow = q0w + q31; if (qrow > 999) qrow = 999;
    s16x8 bq[2];
    #pragma unroll
    for (int dh = 0; dh < 2; ++dh)
        bq[dh] = *(const s16x8*)(qkv + ((size_t)(b * TT_ + qrow)) * 768 + h * 32 + dh * 16 + hi * 8);

    f32x16 oacc;
    #pragma unroll
    for (int i = 0; i < 16; ++i) oacc[i] = 0.f;
    float lrun = 0.f;

    const int sr = tid >> 2, sc = tid & 3;
    const int u = tid & 255;
    const int kp = u >> 3, dq = (u & 7) * 4;
    s16x8 kreg;
    short4 va, vb;
    auto LOADT = [&](int kt) {
        if (tid < 256) {
            int t = kt * 64 + sr; if (t > 999) t = 999;
            kreg = *(const s16x8*)(qkv + ((size_t)(b * TT_ + t)) * 768 + 256 + h * 32 + sc * 8);
        } else {
            int t0 = kt * 64 + 2 * kp, t1 = t0 + 1;
            if (t0 > 999) t0 = 999;
            if (t1 > 999) t1 = 999;
            va = *(const short4*)(qkv + ((size_t)(b * TT_ + t0)) * 768 + 512 + h * 32 + dq);
            vb = *(const short4*)(qkv + ((size_t)(b * TT_ + t1)) * 768 + 512 + h * 32 + dq);
        }
    };
    auto WRITET = [&](int buf) {
        if (tid < 256) {
            *(s16x8*)(&Ks[buf][sr * 40 + sc * 8]) = kreg;
        } else {
            const int c = kp >> 2;
            const int ko = (2 * kp) & 7;
            const uint2 vaw = *(const uint2*)&va;
            const uint2 vbw = *(const uint2*)&vb;
            unsigned pk[4];
            pk[0] = __builtin_amdgcn_perm(vbw.x, vaw.x, 0x05040100u);
            pk[1] = __builtin_amdgcn_perm(vbw.x, vaw.x, 0x07060302u);
            pk[2] = __builtin_amdgcn_perm(vbw.y, vaw.y, 0x05040100u);
            pk[3] = __builtin_amdgcn_perm(vbw.y, vaw.y, 0x07060302u);
            #pragma unroll
            for (int j = 0; j < 4; ++j) {
                const int d = dq + j;
                *(unsigned*)(&VT[buf][d * 72 + ((c ^ (d >> 3)) * 8) + ko]) = pk[j];
            }
        }
    };

    LOADT(0); WRITET(0);
    __syncthreads();
    int cur = 0;

    for (int kt = 0; kt < 16; ++kt) {
        if (kt < 15) LOADT(kt + 1);

        f32x16 st[2];
        __builtin_amdgcn_s_setprio(1);
        #pragma unroll
        for (int kb = 0; kb < 2; ++kb) {
            s16x8 kf0 = *(const s16x8*)(&Ks[cur][(kb * 32 + q31) * 40 + hi * 8]);
            s16x8 kf1 = *(const s16x8*)(&Ks[cur][(kb * 32 + q31) * 40 + 16 + hi * 8]);
            f32x16 z;
            #pragma unroll
            for (int i = 0; i < 16; ++i) z[i] = 0.f;
            z = __builtin_amdgcn_mfma_f32_32x32x16_bf16(kf0, bq[0], z, 0, 0, 0);
            z = __builtin_amdgcn_mfma_f32_32x32x16_bf16(kf1, bq[1], z, 0, 0, 0);
            st[kb] = z;
        }
        __builtin_amdgcn_s_setprio(0);

        if (kt == 15) {
            #pragma unroll
            for (int kb = 0; kb < 2; ++kb)
                #pragma unroll
                for (int r = 0; r < 16; ++r) {
                    const int kloc = kb * 32 + (r & 3) + 8 * (r >> 2) + 4 * hi;
                    if (960 + kloc >= TT_) st[kb][r] = -1e30f;
                }
        }

        float sloc = 0.f;
        #pragma unroll
        for (int kb = 0; kb < 2; ++kb)
            #pragma unroll
            for (int r = 0; r < 16; ++r) {
                const float p = exp2i(st[kb][r]);
                st[kb][r] = p; sloc += p;
            }
        lrun += sloc;

        unsigned wk[2][4][2];
        #pragma unroll
        for (int kb = 0; kb < 2; ++kb)
            #pragma unroll
            for (int a = 0; a < 4; ++a)
                #pragma unroll
                for (int h2 = 0; h2 < 2; ++h2) {
                    unsigned rr;
                    asm("v_cvt_pk_bf16_f32 %0, %1, %2"
                        : "=v"(rr)
                        : "v"(st[kb][4 * a + 2 * h2]), "v"(st[kb][4 * a + 2 * h2 + 1]));
                    wk[kb][a][h2] = rr;
                }

        #pragma unroll
        for (int ks = 0; ks < 4; ++ks) {
            const int kb = ks >> 1, qq = ks & 1;
            unsigned X0 = wk[kb][2 * qq + 1][0], Y0 = wk[kb][2 * qq][0];
            unsigned X1 = wk[kb][2 * qq + 1][1], Y1 = wk[kb][2 * qq][1];
            asm("v_permlane32_swap_b32 %0, %1" : "+v"(X0), "+v"(Y0));
            asm("v_permlane32_swap_b32 %0, %1" : "+v"(X1), "+v"(Y1));
            u32x4 w4 = (u32x4){Y0, Y1, X0, X1};
            s16x8 pb = __builtin_bit_cast(s16x8, w4);
            s16x8 vf = *(const s16x8*)(&VT[cur][q31 * 72 + (((2 * ks + hi) ^ (q31 >> 3)) * 8)]);
            __builtin_amdgcn_s_setprio(1);
            oacc = __builtin_amdgcn_mfma_f32_32x32x16_bf16(vf, pb, oacc, 0, 0, 0);
            __builtin_amdgcn_s_setprio(0);
        }

        if (kt < 15) WRITET(cur ^ 1);
        __syncthreads();
        cur ^= 1;
    }

    lrun += __shfl_xor(lrun, 32);

    const int t = q0w + q31;
    if (t < TT_) {
        const float inv = 1.f / lrun;
        short* ob = o + ((size_t)(b * TT_ + t)) * 256 + h * 32;
        #pragma unroll
        for (int a = 0; a < 4; ++a) {
            unsigned w0, w1;
            asm("v_cvt_pk_bf16_f32 %0, %1, %2"
                : "=v"(w0) : "v"(oacc[4 * a + 0] * inv), "v"(oacc[4 * a + 1] * inv));
            asm("v_cvt_pk_bf16_f32 %0, %1, %2"
                : "=v"(w1) : "v"(oacc[4 * a + 2] * inv), "v"(oacc[4 * a + 3] * inv));
            const int d0 = 8 * a + 4 * hi;
            *(unsigned*)(ob + d0) = w0;
            *(unsigned*)(ob + d0 + 2) = w1;
        }
    }
}

// ---------------- mean pool (bf16 input) ----------------
__global__ __launch_bounds__(256) void pool_part_k(const short* __restrict__ Xb,
                                                   float* __restrict__ partial)
{
    const int b = blockIdx.x, seg = blockIdx.y, d = threadIdx.x;
    float s = 0.f;
    const int t0 = seg * 125;
    for (int t = t0; t < t0 + 125; ++t) s += bf2f(Xb[((size_t)b * TT_ + t) * 256 + d]);
    partial[(b * 8 + seg) * 256 + d] = s;
}
__global__ __launch_bounds__(256) void pool_red_k(const float* __restrict__ partial,
                                                  float* __restrict__ pooled)
{
    const int b = blockIdx.x, d = threadIdx.x;
    float s = 0.f;
    for (int k = 0; k < 8; ++k) s += partial[(b * 8 + k) * 256 + d];
    pooled[b * 256 + d] = s * (1.f / (float)TT_);
}

// ---------------- decode head ----------------
__global__ __launch_bounds__(128) void head_k(const float* __restrict__ pooled,
                                              const float* __restrict__ toLW,
                                              const float* __restrict__ toLb,
                                              const float* __restrict__ dW1,
                                              const float* __restrict__ db1,
                                              const float* __restrict__ dW2,
                                              const float* __restrict__ db2,
                                              float* __restrict__ coeffs)
{
    const int b = blockIdx.x, j = threadIdx.x;
    __shared__ float hs[64];
    __shared__ float hid[128];
    float a = toLb[j];
    for (int d = 0; d < 256; ++d) a += pooled[b * 256 + d] * toLW[d * 128 + j];
    if (j < 64) hs[j] = a;
    __syncthreads();
    float a2 = db1[j];
    for (int z = 0; z < 64; ++z) a2 += hs[z] * dW1[z * 128 + j];
    hid[j] = fmaxf(a2, 0.f);
    __syncthreads();
    if (j < 120) {
        float a3 = db2[j];
        for (int k = 0; k < 128; ++k) a3 += hid[k] * dW2[k * 120 + j];
        coeffs[b * 120 + j] = a3;
    }
}

// ---------------- combined conv kernel ----------------
__global__ void comb_k(const float* __restrict__ selfK,
                       const float* __restrict__ cplW,
                       const float* __restrict__ cplB,
                       float* __restrict__ comb)
{
    const int n = threadIdx.x;
    for (int ti = 0; ti < 20; ++ti) {
        float s = selfK[ti * 256 + n];
        #pragma unroll
        for (int si = 0; si < 4; ++si) s += cplW[n * 4 + si] * cplB[ti * 4 + si];
        comb[n * 20 + ti] = s;
    }
}

// ---------------- sti_lat ----------------
__global__ __launch_bounds__(256) void stilat_k(const float* __restrict__ SB,
                                                const float* __restrict__ coeffs,
                                                float* __restrict__ STL)
{
    const int bf = blockIdx.x;
    __shared__ float c[30];
    if (threadIdx.x < 30) c[threadIdx.x] = coeffs[(bf >> 2) * 120 + (bf & 3) * 30 + threadIdx.x];
    __syncthreads();
    for (int t = threadIdx.x; t < TT_; t += 256) {
        float acc = 0.f;
        const float* sp = SB + (size_t)t * 30;
        #pragma unroll
        for (int k = 0; k < 30; ++k) acc += c[k] * sp[k];
        STL[bf * TT_ + t] = acc;
    }
}

// ---------------- final ----------------
__global__ __launch_bounds__(256) void final_k(const float* __restrict__ Y,
                                               const float* __restrict__ STL,
                                               const float* __restrict__ roW,
                                               const float* __restrict__ comb,
                                               float* __restrict__ out)
{
    const int bx = blockIdx.x;
    const int ts = bx & 3, nc = (bx >> 2) & 31, b = bx >> 7;
    const int n0 = nc * 8, t0 = ts * 250;
    const int tid = threadIdx.x;
    __shared__ float rw[8][4], ck[8][20], yl[8][272];

    if (tid < 32) rw[tid >> 2][tid & 3] = roW[(n0 + (tid >> 2)) * 4 + (tid & 3)];
    if (tid >= 64 && tid < 224) {
        const int j = tid - 64;
        ck[j / 20][j % 20] = comb[(n0 + j / 20) * 20 + (j % 20)];
    }
    for (int j = tid; j < 2160; j += 256) {
        const int n = j / 270, jj = j - n * 270;
        yl[n][jj] = Y[((size_t)(b * 256 + n0 + n)) * TTOT_ + t0 + 80 + jj];
    }
    __syncthreads();

    if (tid < 250) {
        const int t = t0 + tid;
        float s4[4];
        #pragma unroll
        for (int f = 0; f < 4; ++f) s4[f] = STL[((size_t)b * 4 + f) * TT_ + t];
        #pragma unroll
        for (int n = 0; n < 8; ++n) {
            float acc = rw[n][0] * s4[0] + rw[n][1] * s4[1]
                      + rw[n][2] * s4[2] + rw[n][3] * s4[3];
            #pragma unroll
            for (int tau = 1; tau <= 20; ++tau)
                acc += ck[n][tau - 1] * yl[n][tid + 20 - tau];
            out[((size_t)(b * 256 + n0 + n)) * TT_ + t] = acc;
        }
    }
}

// ---------------- launch ----------------
extern "C" void kernel_launch(void* const* d_in, const int* in_sizes, int n_in,
                              void* d_out, int out_size, void* d_ws, size_t ws_size,
                              hipStream_t stream)
{
    const float* Y      = (const float*)d_in[0];
    const float* tokW   = (const float*)d_in[1];
    const float* tokb   = (const float*)d_in[2];
    const float* Wqkv   = (const float*)d_in[3];
    const float* bqkv   = (const float*)d_in[4];
    const float* Wo     = (const float*)d_in[5];
    const float* bo     = (const float*)d_in[6];
    const float* ln1g   = (const float*)d_in[7];
    const float* ln1b   = (const float*)d_in[8];
    const float* W1     = (const float*)d_in[9];
    const float* b1     = (const float*)d_in[10];
    const float* W2     = (const float*)d_in[11];
    const float* b2     = (const float*)d_in[12];
    const float* ln2g   = (const float*)d_in[13];
    const float* ln2b   = (const float*)d_in[14];
    const float* toLW   = (const float*)d_in[15];
    const float* toLb   = (const float*)d_in[16];
    const float* dW1    = (const float*)d_in[17];
    const float* db1    = (const float*)d_in[18];
    const float* dW2    = (const float*)d_in[19];
    const float* db2    = (const float*)d_in[20];
    const float* SB     = (const float*)d_in[21];
    const float* roW    = (const float*)d_in[22];
    const float* cplW   = (const float*)d_in[23];
    const float* cplB   = (const float*)d_in[24];
    const float* selfK  = (const float*)d_in[25];

    float* ws  = (float*)d_ws;
    short* Xb  = (short*)(ws + XB_OFF);
    short* O   = (short*)(ws + O_OFF);
    short* BIG = (short*)(ws + BIG_OFF);
    short* WT  = (short*)(ws + WT_OFF);
    float* PE  = ws + PE_OFF;
    float* PP  = ws + PP_OFF;
    float* PL  = ws + PL_OFF;
    float* CF  = ws + CF_OFF;
    float* CB  = ws + CB_OFF;
    float* BQ  = ws + BQ_OFF;
    float* STL = ws + STL_OFF;

    short* WTqkv = WT;
    short* WTo   = WT + 786432;
    short* WTw1  = WT + 1048576;
    short* WTw2  = WT + 2097152;
    short* WTtok = WT + 3145728;
    short* Ybt   = BIG;

    wtr_k<<<dim3(24, 8, 4), 256, 0, stream>>>(Wqkv, WTqkv, 256, 768, 256, SC2_);
    wtr_k<<<dim3(8, 8, 4),  256, 0, stream>>>(Wo,   WTo,   256, 256, 0, 1.f);
    wtr_k<<<dim3(32, 8, 4), 256, 0, stream>>>(W1,   WTw1,  256, 1024, 0, 1.f);
    wtr_k<<<dim3(8, 32, 4), 256, 0, stream>>>(W2,   WTw2,  1024, 256, 0, 1.f);
    wtr_k<<<dim3(8, 8, 1),  256, 0, stream>>>(tokW, WTtok, 256, 256, 0, 1.f);
    bscale_k<<<12, 256, 0, stream>>>(bqkv, BQ);
    pe_k<<<1000, 256, 0, stream>>>(PE);
    ytr_k<<<dim3(32, 8, 16), 256, 0, stream>>>(Y, Ybt);

    bgemm_emb_k<<<500, 256, 0, stream>>>(
        Ybt, WTtok, tokb, PE, Xb, 16000, 256, 256, 2);

    for (int l = 0; l < 4; ++l) {
        bgemm_sb_k<0, 0><<<1500, 256, 0, stream>>>(
            Xb, WTqkv + (size_t)l * 196608, BQ + l * 768, BIG,
            16000, 768, 256, 6);
        mattn_k<<<512, 512, 0, stream>>>(BIG, O);
        bgemmln_k<<<500, 512, 0, stream>>>(
            O, WTo + (size_t)l * 65536, bo + l * 256,
            ln1g + l * 256, ln1b + l * 256, Xb, 256);
        bgemm_sb_k<1, 1><<<2000, 256, 0, stream>>>(
            Xb, WTw1 + (size_t)l * 262144, b1 + l * 1024, BIG,
            16000, 1024, 256, 8);
        bgemmln_k<<<500, 512, 0, stream>>>(
            BIG, WTw2 + (size_t)l * 262144, b2 + l * 256,
            ln2g + l * 256, ln2b + l * 256, Xb, 1024);
    }

    pool_part_k<<<dim3(16, 8), 256, 0, stream>>>(Xb, PP);
    pool_red_k<<<16, 256, 0, stream>>>(PP, PL);
    head_k<<<16, 128, 0, stream>>>(PL, toLW, toLb, dW1, db1, dW2, db2, CF);
    comb_k<<<1, 256, 0, stream>>>(selfK, cplW, cplB, CB);
    stilat_k<<<64, 256, 0, stream>>>(SB, CF, STL);
    final_k<<<2048, 256, 0, stream>>>(Y, STL, roW, CB, (float*)d_out);
}